// Round 1
// baseline (1563.870 us; speedup 1.0000x reference)
//
#include <hip/hip_runtime.h>
#include <math.h>

#define TOK 8192
#define DM 1024
#define EPSF 1e-5f

// ---------------- LayerNorm (one block per row) ----------------
__global__ __launch_bounds__(256) void ln_k(const float* __restrict__ x,
                                            const float* __restrict__ g,
                                            const float* __restrict__ b,
                                            float* __restrict__ xn) {
  __shared__ float red[8];
  int row = blockIdx.x;
  const float4* xr = (const float4*)(x + (size_t)row * DM);
  float4 v = xr[threadIdx.x];
  float s = v.x + v.y + v.z + v.w;
#pragma unroll
  for (int o = 32; o > 0; o >>= 1) s += __shfl_down(s, o, 64);
  int lane = threadIdx.x & 63, w = threadIdx.x >> 6;
  if (lane == 0) red[w] = s;
  __syncthreads();
  float mu = (red[0] + red[1] + red[2] + red[3]) * (1.0f / DM);
  float dx = v.x - mu, dy = v.y - mu, dz = v.z - mu, dw = v.w - mu;
  float ss = dx * dx + dy * dy + dz * dz + dw * dw;
#pragma unroll
  for (int o = 32; o > 0; o >>= 1) ss += __shfl_down(ss, o, 64);
  if (lane == 0) red[4 + w] = ss;
  __syncthreads();
  float var = (red[4] + red[5] + red[6] + red[7]) * (1.0f / DM);
  float rstd = rsqrtf(var + EPSF);
  float4 gg = ((const float4*)g)[threadIdx.x];
  float4 bb = ((const float4*)b)[threadIdx.x];
  float4 o4;
  o4.x = dx * rstd * gg.x + bb.x;
  o4.y = dy * rstd * gg.y + bb.y;
  o4.z = dz * rstd * gg.z + bb.z;
  o4.w = dw * rstd * gg.w + bb.w;
  ((float4*)(xn + (size_t)row * DM))[threadIdx.x] = o4;
}

// ---------------- gate row-mean normalize (post-sigmoid) ----------------
__global__ __launch_bounds__(256) void gatenorm_k(float* __restrict__ gate) {
  __shared__ float red[4];
  int row = blockIdx.x;
  float4* gr = (float4*)(gate + (size_t)row * DM);
  float4 v = gr[threadIdx.x];
  float s = v.x + v.y + v.z + v.w;
#pragma unroll
  for (int o = 32; o > 0; o >>= 1) s += __shfl_down(s, o, 64);
  int lane = threadIdx.x & 63, w = threadIdx.x >> 6;
  if (lane == 0) red[w] = s;
  __syncthreads();
  float mean = (red[0] + red[1] + red[2] + red[3]) * (1.0f / DM);
  float inv = 1.0f / (mean + EPSF);
  v.x *= inv; v.y *= inv; v.z *= inv; v.w *= inv;
  gr[threadIdx.x] = v;
}

// ---------------- generic fp32 tiled GEMM: C = A@W + bias, epilogue modes --
// mode 0: plain.  mode 1: qkv feature epilogue (gate*, relu^2 + eps on cols<2048).
// mode 2: sigmoid.
__global__ __launch_bounds__(256) void gemm_k(const float* __restrict__ A, int lda,
                                              const float* __restrict__ W,
                                              const float* __restrict__ bias,
                                              float* __restrict__ C, int ldc,
                                              int M, int N, int K,
                                              int mode, const float* __restrict__ gate) {
  __shared__ float As[16][65];  // [k][m], padded
  __shared__ float Bs[16][64];  // [k][n]
  int tid = threadIdx.x;
  int tx = tid & 15, ty = tid >> 4;
  int m0 = blockIdx.y * 64, n0 = blockIdx.x * 64;
  int am = tid >> 2, ak = (tid & 3) << 2;
  int bn = tid & 63, bk0 = (tid >> 6) << 2;
  float acc[4][4] = {};
  for (int k0 = 0; k0 < K; k0 += 16) {
    float4 a4 = *(const float4*)&A[(size_t)(m0 + am) * lda + k0 + ak];
    As[ak + 0][am] = a4.x;
    As[ak + 1][am] = a4.y;
    As[ak + 2][am] = a4.z;
    As[ak + 3][am] = a4.w;
#pragma unroll
    for (int i = 0; i < 4; i++)
      Bs[bk0 + i][bn] = W[(size_t)(k0 + bk0 + i) * N + n0 + bn];
    __syncthreads();
#pragma unroll
    for (int kk = 0; kk < 16; kk++) {
      float a0 = As[kk][ty * 4 + 0];
      float a1 = As[kk][ty * 4 + 1];
      float a2 = As[kk][ty * 4 + 2];
      float a3 = As[kk][ty * 4 + 3];
      float4 b4 = *(const float4*)&Bs[kk][tx * 4];
      acc[0][0] += a0 * b4.x; acc[0][1] += a0 * b4.y; acc[0][2] += a0 * b4.z; acc[0][3] += a0 * b4.w;
      acc[1][0] += a1 * b4.x; acc[1][1] += a1 * b4.y; acc[1][2] += a1 * b4.z; acc[1][3] += a1 * b4.w;
      acc[2][0] += a2 * b4.x; acc[2][1] += a2 * b4.y; acc[2][2] += a2 * b4.z; acc[2][3] += a2 * b4.w;
      acc[3][0] += a3 * b4.x; acc[3][1] += a3 * b4.y; acc[3][2] += a3 * b4.z; acc[3][3] += a3 * b4.w;
    }
    __syncthreads();
  }
#pragma unroll
  for (int i = 0; i < 4; i++) {
    int row = m0 + ty * 4 + i;
#pragma unroll
    for (int j = 0; j < 4; j++) {
      int col = n0 + tx * 4 + j;
      float v = acc[i][j] + bias[col];
      if (mode == 1) {
        if (col < 2048) {
          float gv = gate[(size_t)row * DM + (col & 1023)];
          v *= gv;
          v = fmaxf(v, 0.0f);
          v = v * v + EPSF;
        }
      } else if (mode == 2) {
        v = 1.0f / (1.0f + expf(-v));
      }
      C[(size_t)row * ldc + col] = v;
    }
  }
}

// ---------------- pass 1: per-chunk KV = K^T V and Ksum ----------------
// grid (32 chunks, 64 bh), block 64 threads (thread = dk row of KV)
__global__ __launch_bounds__(64) void chunkkv_k(const float* __restrict__ qkv,
                                                float* __restrict__ stateKV,
                                                float* __restrict__ stateKs) {
  int c = blockIdx.x, bh = blockIdx.y;
  int b = bh >> 4, h = bh & 15;
  size_t row0 = (size_t)b * 2048 + (size_t)c * 64;
  const float* Kp = qkv + row0 * 3072 + 1024 + h * 64;
  const float* Vp = qkv + row0 * 3072 + 2048 + h * 64;
  __shared__ float Kl[64][64];
  __shared__ float Vl[64][64];
  int tid = threadIdx.x;
  for (int t = 0; t < 64; t++) {
    Kl[t][tid] = Kp[(size_t)t * 3072 + tid];
    Vl[t][tid] = Vp[(size_t)t * 3072 + tid];
  }
  __syncthreads();
  float4 kv[16];
#pragma unroll
  for (int m = 0; m < 16; m++) kv[m] = make_float4(0.f, 0.f, 0.f, 0.f);
  float ks = 0.0f;
  for (int t = 0; t < 64; t++) {
    float kval = Kl[t][tid];
    ks += kval;
    const float4* v4 = (const float4*)Vl[t];
#pragma unroll
    for (int m = 0; m < 16; m++) {
      float4 vv = v4[m];
      kv[m].x += kval * vv.x; kv[m].y += kval * vv.y;
      kv[m].z += kval * vv.z; kv[m].w += kval * vv.w;
    }
  }
  float* dst = stateKV + ((size_t)bh * 32 + c) * 4096 + (size_t)tid * 64;
#pragma unroll
  for (int m = 0; m < 16; m++) ((float4*)dst)[m] = kv[m];
  stateKs[((size_t)bh * 32 + c) * 64 + tid] = ks;
}

// ---------------- pass 2: exclusive prefix over chunks, in place ----------
// grid (64 bh, 17 slices of 256 elems), block 256
__global__ __launch_bounds__(256) void prefix_k(float* __restrict__ stateKV,
                                                float* __restrict__ stateKs) {
  int bh = blockIdx.x;
  int gid = blockIdx.y * 256 + threadIdx.x;
  float run = 0.0f;
  if (gid < 4096) {
    for (int c = 0; c < 32; c++) {
      size_t idx = ((size_t)bh * 32 + c) * 4096 + gid;
      float v = stateKV[idx];
      stateKV[idx] = run;
      run += v;
    }
  } else if (gid < 4160) {
    int d = gid - 4096;
    for (int c = 0; c < 32; c++) {
      size_t idx = ((size_t)bh * 32 + c) * 64 + d;
      float v = stateKs[idx];
      stateKs[idx] = run;
      run += v;
    }
  }
}

// ---------------- pass 3: per-chunk output, overwrites V slice in-place ---
// grid (32 chunks, 64 bh), block 256 (4 waves; thread = (row t, m-partition p))
__global__ __launch_bounds__(256) void attn_k(float* __restrict__ qkv,
                                              const float* __restrict__ stateKV,
                                              const float* __restrict__ stateKs) {
  int c = blockIdx.x, bh = blockIdx.y;
  int b = bh >> 4, h = bh & 15;
  size_t row0 = (size_t)b * 2048 + (size_t)c * 64;
  const float* Qp = qkv + row0 * 3072 + h * 64;
  const float* Kp = Qp + 1024;
  float* Vp = (float*)(Qp + 2048);
  __shared__ float QT[64][65];   // transposed Q, padded
  __shared__ float Kl[64][64];
  __shared__ float Vl[64][64];
  __shared__ float Sl[64][65];   // scores [t][s], padded
  __shared__ float denl[4][64];
  __shared__ float ksl[64];
  int tid = threadIdx.x;
#pragma unroll
  for (int i = 0; i < 16; i++) {
    int e = tid + i * 256;
    int r = e >> 6, col = e & 63;
    QT[col][r] = Qp[(size_t)r * 3072 + col];
    Kl[r][col] = Kp[(size_t)r * 3072 + col];
    Vl[r][col] = Vp[(size_t)r * 3072 + col];
  }
  if (tid < 64) ksl[tid] = stateKs[((size_t)bh * 32 + c) * 64 + tid];
  __syncthreads();
  int t = tid & 63, p = tid >> 6;
  float q[64];
#pragma unroll
  for (int d = 0; d < 64; d++) q[d] = QT[d][t];
  // scores for s in [p*16, p*16+16), causal mask s<=t
  float dpart = 0.0f;
#pragma unroll
  for (int j = 0; j < 16; j++) {
    int s = p * 16 + j;
    const float4* k4 = (const float4*)Kl[s];
    float acc = 0.0f;
#pragma unroll
    for (int d4 = 0; d4 < 16; d4++) {
      float4 kk = k4[d4];
      acc += q[d4 * 4 + 0] * kk.x + q[d4 * 4 + 1] * kk.y +
             q[d4 * 4 + 2] * kk.z + q[d4 * 4 + 3] * kk.w;
    }
    acc = (s <= t) ? acc : 0.0f;
    Sl[t][s] = acc;
    dpart += acc;
  }
  denl[p][t] = dpart;
  float dp = 0.0f;
#pragma unroll
  for (int d = 0; d < 64; d++) dp += q[d] * ksl[d];
  __syncthreads();
  float den = dp + denl[0][t] + denl[1][t] + denl[2][t] + denl[3][t] + EPSF;
  float inv = 1.0f / den;
  const float* KVp = stateKV + ((size_t)bh * 32 + c) * 4096;
#pragma unroll
  for (int mc = 0; mc < 4; mc++) {
    int m = p * 16 + mc * 4;
    float4 o = make_float4(0.f, 0.f, 0.f, 0.f);
#pragma unroll
    for (int d = 0; d < 64; d++) {
      float4 kv = *(const float4*)&KVp[(size_t)d * 64 + m];
      float qd = q[d];
      o.x += qd * kv.x; o.y += qd * kv.y; o.z += qd * kv.z; o.w += qd * kv.w;
    }
#pragma unroll
    for (int s = 0; s < 64; s++) {
      float sv = Sl[t][s];
      const float4 vv = *(const float4*)&Vl[s][m];
      o.x += sv * vv.x; o.y += sv * vv.y; o.z += sv * vv.z; o.w += sv * vv.w;
    }
    o.x *= inv; o.y *= inv; o.z *= inv; o.w *= inv;
    *(float4*)&Vp[(size_t)t * 3072 + m] = o;  // overwrite V slice with output
  }
}

extern "C" void kernel_launch(void* const* d_in, const int* in_sizes, int n_in,
                              void* d_out, int out_size, void* d_ws, size_t ws_size,
                              hipStream_t stream) {
  const float* x      = (const float*)d_in[0];
  const float* ln_g   = (const float*)d_in[1];
  const float* ln_b   = (const float*)d_in[2];
  const float* W_qkv  = (const float*)d_in[3];
  const float* b_qkv  = (const float*)d_in[4];
  const float* W_gate = (const float*)d_in[5];
  const float* b_gate = (const float*)d_in[6];
  const float* W_proj = (const float*)d_in[7];
  const float* b_proj = (const float*)d_in[8];
  float* out = (float*)d_out;

  float* ws   = (float*)d_ws;
  float* xn   = ws;                        // TOK*DM; later reused for Ksum states
  float* gate = ws + (size_t)TOK * DM;     // TOK*DM; later reused for KV states
  float* qkv  = gate + (size_t)TOK * DM;   // TOK*3*DM; V third overwritten by attn out
  float* stateKV = gate;                   // 64*32*4096 floats == TOK*DM exactly
  float* stateKs = xn;                     // 64*32*64 floats

  // 1) LayerNorm
  ln_k<<<TOK, 256, 0, stream>>>(x, ln_g, ln_b, xn);
  // 2) gate = sigmoid(x @ W_gate + b_gate)
  gemm_k<<<dim3(DM / 64, TOK / 64), 256, 0, stream>>>(x, DM, W_gate, b_gate, gate, DM,
                                                      TOK, DM, DM, 2, nullptr);
  // 3) gate /= (row-mean + eps)
  gatenorm_k<<<TOK, 256, 0, stream>>>(gate);
  // 4) qkv = xn @ W_qkv + b_qkv, fused gate*(q,k) then relu^2+eps
  gemm_k<<<dim3(3 * DM / 64, TOK / 64), 256, 0, stream>>>(xn, DM, W_qkv, b_qkv, qkv, 3 * DM,
                                                          TOK, 3 * DM, DM, 1, gate);
  // 5) per-chunk KV/Ksum states
  chunkkv_k<<<dim3(32, 64), 64, 0, stream>>>(qkv, stateKV, stateKs);
  // 6) exclusive prefix over chunks
  prefix_k<<<dim3(64, 17), 256, 0, stream>>>(stateKV, stateKs);
  // 7) chunk outputs (writes into V slice of qkv)
  attn_k<<<dim3(32, 64), 256, 0, stream>>>(qkv, stateKV, stateKs);
  // 8) out = attn @ W_proj + b_proj
  gemm_k<<<dim3(DM / 64, TOK / 64), 256, 0, stream>>>(qkv + 2 * DM, 3 * DM, W_proj, b_proj,
                                                      out, DM, TOK, DM, DM, 0, nullptr);
}

// Round 2
// 449.870 us; speedup vs baseline: 3.4763x; 3.4763x over previous
//
#include <hip/hip_runtime.h>
#include <math.h>

#define TOK 8192
#define DM 1024
#define EPSF 1e-5f

typedef __attribute__((ext_vector_type(8))) short short8;
typedef __attribute__((ext_vector_type(4))) float f32x4;

static __device__ __forceinline__ ushort f2bf(float f) {
  unsigned u = __float_as_uint(f);
  unsigned r = (u + 0x7fffu + ((u >> 16) & 1u)) >> 16;
  return (ushort)r;
}

static __device__ __forceinline__ void gload_lds16(const ushort* g, ushort* l) {
  __builtin_amdgcn_global_load_lds((const __attribute__((address_space(1))) void*)g,
                                   (__attribute__((address_space(3))) void*)l, 16, 0, 0);
}

// ---------------- fp32 -> bf16 convert ----------------
__global__ __launch_bounds__(256) void cvt_k(const float* __restrict__ in,
                                             ushort* __restrict__ out, int n4) {
  for (int i = blockIdx.x * 256 + threadIdx.x; i < n4; i += gridDim.x * 256) {
    float4 v = ((const float4*)in)[i];
    ushort4 o;
    o.x = f2bf(v.x); o.y = f2bf(v.y); o.z = f2bf(v.z); o.w = f2bf(v.w);
    ((ushort4*)out)[i] = o;
  }
}

// ---------------- W [K][N] fp32 -> Wt [N][K] bf16 ----------------
__global__ __launch_bounds__(256) void tconv_k(const float* __restrict__ W,
                                               ushort* __restrict__ Wt, int K, int N) {
  __shared__ ushort tile[32][33];
  int k0 = blockIdx.y * 32, n0 = blockIdx.x * 32;
  int tx = threadIdx.x & 31, ty = threadIdx.x >> 5;
#pragma unroll
  for (int i = 0; i < 4; i++) {
    int k = ty + i * 8;
    tile[k][tx] = f2bf(W[(size_t)(k0 + k) * N + n0 + tx]);
  }
  __syncthreads();
#pragma unroll
  for (int i = 0; i < 4; i++) {
    int n = ty + i * 8;
    Wt[(size_t)(n0 + n) * K + k0 + tx] = tile[tx][n];
  }
}

// ---------------- LayerNorm -> bf16 output ----------------
__global__ __launch_bounds__(256) void ln_k(const float* __restrict__ x,
                                            const float* __restrict__ g,
                                            const float* __restrict__ b,
                                            ushort* __restrict__ xn_b) {
  __shared__ float red[8];
  int row = blockIdx.x;
  const float4* xr = (const float4*)(x + (size_t)row * DM);
  float4 v = xr[threadIdx.x];
  float s = v.x + v.y + v.z + v.w;
#pragma unroll
  for (int o = 32; o > 0; o >>= 1) s += __shfl_down(s, o, 64);
  int lane = threadIdx.x & 63, w = threadIdx.x >> 6;
  if (lane == 0) red[w] = s;
  __syncthreads();
  float mu = (red[0] + red[1] + red[2] + red[3]) * (1.0f / DM);
  float dx = v.x - mu, dy = v.y - mu, dz = v.z - mu, dw = v.w - mu;
  float ss = dx * dx + dy * dy + dz * dz + dw * dw;
#pragma unroll
  for (int o = 32; o > 0; o >>= 1) ss += __shfl_down(ss, o, 64);
  if (lane == 0) red[4 + w] = ss;
  __syncthreads();
  float var = (red[4] + red[5] + red[6] + red[7]) * (1.0f / DM);
  float rstd = rsqrtf(var + EPSF);
  float4 gg = ((const float4*)g)[threadIdx.x];
  float4 bb = ((const float4*)b)[threadIdx.x];
  ushort4 o4;
  o4.x = f2bf(dx * rstd * gg.x + bb.x);
  o4.y = f2bf(dy * rstd * gg.y + bb.y);
  o4.z = f2bf(dz * rstd * gg.z + bb.z);
  o4.w = f2bf(dw * rstd * gg.w + bb.w);
  ((ushort4*)(xn_b + (size_t)row * DM))[threadIdx.x] = o4;
}

// ---------------- gate row-mean normalize (post-sigmoid, fp32) ------------
__global__ __launch_bounds__(256) void gatenorm_k(float* __restrict__ gate) {
  __shared__ float red[4];
  int row = blockIdx.x;
  float4* gr = (float4*)(gate + (size_t)row * DM);
  float4 v = gr[threadIdx.x];
  float s = v.x + v.y + v.z + v.w;
#pragma unroll
  for (int o = 32; o > 0; o >>= 1) s += __shfl_down(s, o, 64);
  int lane = threadIdx.x & 63, w = threadIdx.x >> 6;
  if (lane == 0) red[w] = s;
  __syncthreads();
  float mean = (red[0] + red[1] + red[2] + red[3]) * (1.0f / DM);
  float inv = 1.0f / (mean + EPSF);
  v.x *= inv; v.y *= inv; v.z *= inv; v.w *= inv;
  gr[threadIdx.x] = v;
}

// ---------------- bf16 MFMA GEMM: C = A @ Wt^T + bias ----------------
// A [M][K] bf16, Bt [N][K] bf16 (pre-transposed W). 128x128 tile, BK=64,
// 4 waves, global_load_lds w=16, XOR-swizzled LDS (u = r*8 + (kb ^ (r&7))).
// mode 0: plain. mode 1: cols<2048 get gate* + relu^2 + eps. mode 2: sigmoid.
#define BM 128
#define BN 128
#define BK 64
__global__ __launch_bounds__(256) void gemm_bf16_k(
    const ushort* __restrict__ A, const ushort* __restrict__ Bt,
    const float* __restrict__ bias, float* __restrict__ C, int ldc,
    int N, int K, int mode, const float* __restrict__ gate) {
  __shared__ __align__(16) ushort As[BM * BK];
  __shared__ __align__(16) ushort Bs[BN * BK];
  int tid = threadIdx.x, lane = tid & 63, w = tid >> 6;
  int m0 = blockIdx.y * BM, n0 = blockIdx.x * BN;
  int wr = w >> 1, wc = w & 1;
  f32x4 acc[4][4] = {};
  for (int k0 = 0; k0 < K; k0 += BK) {
#pragma unroll
    for (int j = 0; j < 4; j++) {
      int lu = (w * 4 + j) * 64 + lane;
      int r = lu >> 3;
      int kb = (lu & 7) ^ (r & 7);  // inverse swizzle on global source
      gload_lds16(A + (size_t)(m0 + r) * K + k0 + kb * 8, &As[(w * 4 + j) * 512]);
      gload_lds16(Bt + (size_t)(n0 + r) * K + k0 + kb * 8, &Bs[(w * 4 + j) * 512]);
    }
    __syncthreads();  // compiler emits vmcnt(0) drain before barrier
#pragma unroll
    for (int ks = 0; ks < 2; ks++) {
      short8 af[4], bfr[4];
      int kq = ks * 4 + (lane >> 4);
#pragma unroll
      for (int f = 0; f < 4; f++) {
        int ra = wr * 64 + f * 16 + (lane & 15);
        af[f] = *(const short8*)&As[(ra * 8 + (kq ^ (ra & 7))) * 8];
        int rb = wc * 64 + f * 16 + (lane & 15);
        bfr[f] = *(const short8*)&Bs[(rb * 8 + (kq ^ (rb & 7))) * 8];
      }
#pragma unroll
      for (int i = 0; i < 4; i++)
#pragma unroll
        for (int j2 = 0; j2 < 4; j2++)
          acc[i][j2] = __builtin_amdgcn_mfma_f32_16x16x32_bf16(af[i], bfr[j2], acc[i][j2], 0, 0, 0);
    }
    __syncthreads();
  }
#pragma unroll
  for (int i = 0; i < 4; i++) {
#pragma unroll
    for (int j2 = 0; j2 < 4; j2++) {
      int col = n0 + wc * 64 + j2 * 16 + (lane & 15);
      float bv = bias[col];
#pragma unroll
      for (int r = 0; r < 4; r++) {
        int row = m0 + wr * 64 + i * 16 + (lane >> 4) * 4 + r;
        float v = acc[i][j2][r] + bv;
        if (mode == 1) {
          if (col < 2048) {
            float gv = gate[(size_t)row * DM + (col & 1023)];
            v *= gv;
            v = fmaxf(v, 0.0f);
            v = v * v + EPSF;
          }
        } else if (mode == 2) {
          v = 1.0f / (1.0f + expf(-v));
        }
        C[(size_t)row * ldc + col] = v;
      }
    }
  }
}

// ---------------- pass 1: per-chunk KV = K^T V and Ksum ----------------
__global__ __launch_bounds__(64) void chunkkv_k(const float* __restrict__ qkv,
                                                float* __restrict__ stateKV,
                                                float* __restrict__ stateKs) {
  int c = blockIdx.x, bh = blockIdx.y;
  int b = bh >> 4, h = bh & 15;
  size_t row0 = (size_t)b * 2048 + (size_t)c * 64;
  const float* Kp = qkv + row0 * 3072 + 1024 + h * 64;
  const float* Vp = qkv + row0 * 3072 + 2048 + h * 64;
  __shared__ float Kl[64][64];
  __shared__ float Vl[64][64];
  int tid = threadIdx.x;
  for (int t = 0; t < 64; t++) {
    Kl[t][tid] = Kp[(size_t)t * 3072 + tid];
    Vl[t][tid] = Vp[(size_t)t * 3072 + tid];
  }
  __syncthreads();
  float4 kv[16];
#pragma unroll
  for (int m = 0; m < 16; m++) kv[m] = make_float4(0.f, 0.f, 0.f, 0.f);
  float ks = 0.0f;
  for (int t = 0; t < 64; t++) {
    float kval = Kl[t][tid];
    ks += kval;
    const float4* v4 = (const float4*)Vl[t];
#pragma unroll
    for (int m = 0; m < 16; m++) {
      float4 vv = v4[m];
      kv[m].x += kval * vv.x; kv[m].y += kval * vv.y;
      kv[m].z += kval * vv.z; kv[m].w += kval * vv.w;
    }
  }
  float* dst = stateKV + ((size_t)bh * 32 + c) * 4096 + (size_t)tid * 64;
#pragma unroll
  for (int m = 0; m < 16; m++) ((float4*)dst)[m] = kv[m];
  stateKs[((size_t)bh * 32 + c) * 64 + tid] = ks;
}

// ---------------- pass 2: exclusive prefix over chunks, in place ----------
__global__ __launch_bounds__(256) void prefix_k(float* __restrict__ stateKV,
                                                float* __restrict__ stateKs) {
  int bh = blockIdx.x;
  int gid = blockIdx.y * 256 + threadIdx.x;
  float run = 0.0f;
  if (gid < 4096) {
    for (int c = 0; c < 32; c++) {
      size_t idx = ((size_t)bh * 32 + c) * 4096 + gid;
      float v = stateKV[idx];
      stateKV[idx] = run;
      run += v;
    }
  } else if (gid < 4160) {
    int d = gid - 4096;
    for (int c = 0; c < 32; c++) {
      size_t idx = ((size_t)bh * 32 + c) * 64 + d;
      float v = stateKs[idx];
      stateKs[idx] = run;
      run += v;
    }
  }
}

// ---------------- pass 3: per-chunk output -> bf16 attnout ----------------
__global__ __launch_bounds__(256) void attn_k(const float* __restrict__ qkv,
                                              const float* __restrict__ stateKV,
                                              const float* __restrict__ stateKs,
                                              ushort* __restrict__ attnout) {
  int c = blockIdx.x, bh = blockIdx.y;
  int b = bh >> 4, h = bh & 15;
  size_t row0 = (size_t)b * 2048 + (size_t)c * 64;
  const float* Qp = qkv + row0 * 3072 + h * 64;
  const float* Kp = Qp + 1024;
  const float* Vp = Qp + 2048;
  __shared__ float QT[64][65];
  __shared__ float Kl[64][64];
  __shared__ float Vl[64][64];
  __shared__ float Sl[64][65];
  __shared__ float denl[4][64];
  __shared__ float ksl[64];
  int tid = threadIdx.x;
#pragma unroll
  for (int i = 0; i < 16; i++) {
    int e = tid + i * 256;
    int r = e >> 6, col = e & 63;
    QT[col][r] = Qp[(size_t)r * 3072 + col];
    Kl[r][col] = Kp[(size_t)r * 3072 + col];
    Vl[r][col] = Vp[(size_t)r * 3072 + col];
  }
  if (tid < 64) ksl[tid] = stateKs[((size_t)bh * 32 + c) * 64 + tid];
  __syncthreads();
  int t = tid & 63, p = tid >> 6;
  float q[64];
#pragma unroll
  for (int d = 0; d < 64; d++) q[d] = QT[d][t];
  float dpart = 0.0f;
#pragma unroll
  for (int j = 0; j < 16; j++) {
    int s = p * 16 + j;
    const float4* k4 = (const float4*)Kl[s];
    float acc = 0.0f;
#pragma unroll
    for (int d4 = 0; d4 < 16; d4++) {
      float4 kk = k4[d4];
      acc += q[d4 * 4 + 0] * kk.x + q[d4 * 4 + 1] * kk.y +
             q[d4 * 4 + 2] * kk.z + q[d4 * 4 + 3] * kk.w;
    }
    acc = (s <= t) ? acc : 0.0f;
    Sl[t][s] = acc;
    dpart += acc;
  }
  denl[p][t] = dpart;
  float dp = 0.0f;
#pragma unroll
  for (int d = 0; d < 64; d++) dp += q[d] * ksl[d];
  __syncthreads();
  float den = dp + denl[0][t] + denl[1][t] + denl[2][t] + denl[3][t] + EPSF;
  float inv = 1.0f / den;
  const float* KVp = stateKV + ((size_t)bh * 32 + c) * 4096;
#pragma unroll
  for (int mc = 0; mc < 4; mc++) {
    int m = p * 16 + mc * 4;
    float4 o = make_float4(0.f, 0.f, 0.f, 0.f);
#pragma unroll
    for (int d = 0; d < 64; d++) {
      float4 kv = *(const float4*)&KVp[(size_t)d * 64 + m];
      float qd = q[d];
      o.x += qd * kv.x; o.y += qd * kv.y; o.z += qd * kv.z; o.w += qd * kv.w;
    }
#pragma unroll
    for (int s = 0; s < 64; s++) {
      float sv = Sl[t][s];
      const float4 vv = *(const float4*)&Vl[s][m];
      o.x += sv * vv.x; o.y += sv * vv.y; o.z += sv * vv.z; o.w += sv * vv.w;
    }
    ushort4 ob;
    ob.x = f2bf(o.x * inv); ob.y = f2bf(o.y * inv);
    ob.z = f2bf(o.z * inv); ob.w = f2bf(o.w * inv);
    *(ushort4*)&attnout[(size_t)(row0 + t) * 1024 + h * 64 + m] = ob;
  }
}

extern "C" void kernel_launch(void* const* d_in, const int* in_sizes, int n_in,
                              void* d_out, int out_size, void* d_ws, size_t ws_size,
                              hipStream_t stream) {
  const float* x      = (const float*)d_in[0];
  const float* ln_g   = (const float*)d_in[1];
  const float* ln_b   = (const float*)d_in[2];
  const float* W_qkv  = (const float*)d_in[3];
  const float* b_qkv  = (const float*)d_in[4];
  const float* W_gate = (const float*)d_in[5];
  const float* b_gate = (const float*)d_in[6];
  const float* W_proj = (const float*)d_in[7];
  const float* b_proj = (const float*)d_in[8];
  float* out = (float*)d_out;

  // Workspace layout (167.8 MB total, time-sliced aliasing):
  //  off0 [0, 16.8M):    x_b (bf16)        -> Wt_qkv / Wt_proj (@0), stateKs (@8MB)
  //  off1 [16.8M,33.6M): xn_b (bf16)       -> attnout_b (bf16)
  //  off2 [33.6M,67.1M): gate (fp32)       -> stateKV (fp32)
  //  off3 [67.1M,167.8M): qkv (fp32)       (Wt_gate lives here pre-qkv-GEMM)
  char* wsb = (char*)d_ws;
  const size_t TD = (size_t)TOK * DM;
  ushort* x_b     = (ushort*)wsb;
  ushort* xn_b    = (ushort*)(wsb + TD * 2);
  float*  gate    = (float*)(wsb + TD * 4);
  float*  qkv     = (float*)(wsb + TD * 8);
  ushort* Wt_gate = (ushort*)qkv;
  ushort* Wt_qkv  = (ushort*)wsb;
  ushort* Wt_proj = (ushort*)wsb;
  float*  stateKV = gate;
  float*  stateKs = (float*)(wsb + (size_t)8 * 1024 * 1024);
  ushort* attnout = xn_b;

  // 1) x -> bf16
  cvt_k<<<8192, 256, 0, stream>>>(x, x_b, (int)(TD / 4));
  // 2) W_gate -> Wt_gate (transposed bf16)
  tconv_k<<<dim3(DM / 32, DM / 32), 256, 0, stream>>>(W_gate, Wt_gate, DM, DM);
  // 3) gate = sigmoid(x @ W_gate + b_gate)
  gemm_bf16_k<<<dim3(DM / BN, TOK / BM), 256, 0, stream>>>(x_b, Wt_gate, b_gate, gate, DM,
                                                           DM, DM, 2, nullptr);
  // 4) gate /= (row-mean + eps)
  gatenorm_k<<<TOK, 256, 0, stream>>>(gate);
  // 5) LayerNorm -> xn bf16
  ln_k<<<TOK, 256, 0, stream>>>(x, ln_g, ln_b, xn_b);
  // 6) W_qkv -> Wt_qkv (x_b dead)
  tconv_k<<<dim3(3 * DM / 32, DM / 32), 256, 0, stream>>>(W_qkv, Wt_qkv, DM, 3 * DM);
  // 7) qkv = xn @ W_qkv + b_qkv, fused gate*(q,k), relu^2+eps
  gemm_bf16_k<<<dim3(3 * DM / BN, TOK / BM), 256, 0, stream>>>(xn_b, Wt_qkv, b_qkv, qkv, 3 * DM,
                                                               3 * DM, DM, 1, gate);
  // 8) per-chunk KV/Ksum states (gate region dead -> stateKV)
  chunkkv_k<<<dim3(32, 64), 64, 0, stream>>>(qkv, stateKV, stateKs);
  // 9) W_proj -> Wt_proj (Wt_qkv dead)
  tconv_k<<<dim3(DM / 32, DM / 32), 256, 0, stream>>>(W_proj, Wt_proj, DM, DM);
  // 10) exclusive prefix over chunks
  prefix_k<<<dim3(64, 17), 256, 0, stream>>>(stateKV, stateKs);
  // 11) chunk outputs -> attnout bf16 (xn region dead)
  attn_k<<<dim3(32, 64), 256, 0, stream>>>(qkv, stateKV, stateKs, attnout);
  // 12) out = attn @ W_proj + b_proj
  gemm_bf16_k<<<dim3(DM / BN, TOK / BM), 256, 0, stream>>>(attnout, Wt_proj, b_proj, out, DM,
                                                           DM, DM, 0, nullptr);
}

// Round 3
// 235.057 us; speedup vs baseline: 6.6531x; 1.9139x over previous
//
#include <hip/hip_runtime.h>
#include <math.h>

#define TOK 8192
#define DM 1024
#define EPSF 1e-5f

typedef __attribute__((ext_vector_type(8))) short short8;
typedef __attribute__((ext_vector_type(4))) float f32x4;

static __device__ __forceinline__ ushort f2bf(float f) {
  unsigned u = __float_as_uint(f);
  unsigned r = (u + 0x7fffu + ((u >> 16) & 1u)) >> 16;
  return (ushort)r;
}
static __device__ __forceinline__ float bf2f(ushort u) {
  return __uint_as_float((unsigned)u << 16);
}

static __device__ __forceinline__ void gload_lds16(const ushort* g, ushort* l) {
  __builtin_amdgcn_global_load_lds((const __attribute__((address_space(1))) void*)g,
                                   (__attribute__((address_space(3))) void*)l, 16, 0, 0);
}

// ---------------- fp32 -> bf16 convert ----------------
__global__ __launch_bounds__(256) void cvt_k(const float* __restrict__ in,
                                             ushort* __restrict__ out, int n4) {
  for (int i = blockIdx.x * 256 + threadIdx.x; i < n4; i += gridDim.x * 256) {
    float4 v = ((const float4*)in)[i];
    ushort4 o;
    o.x = f2bf(v.x); o.y = f2bf(v.y); o.z = f2bf(v.z); o.w = f2bf(v.w);
    ((ushort4*)out)[i] = o;
  }
}

// ---------------- W [K][N] fp32 -> Wt [N][K] bf16 ----------------
__global__ __launch_bounds__(256) void tconv_k(const float* __restrict__ W,
                                               ushort* __restrict__ Wt, int K, int N) {
  __shared__ ushort tile[32][33];
  int k0 = blockIdx.y * 32, n0 = blockIdx.x * 32;
  int tx = threadIdx.x & 31, ty = threadIdx.x >> 5;
#pragma unroll
  for (int i = 0; i < 4; i++) {
    int k = ty + i * 8;
    tile[k][tx] = f2bf(W[(size_t)(k0 + k) * N + n0 + tx]);
  }
  __syncthreads();
#pragma unroll
  for (int i = 0; i < 4; i++) {
    int n = ty + i * 8;
    Wt[(size_t)(n0 + n) * K + k0 + tx] = tile[tx][n];
  }
}

// ---------------- LayerNorm -> bf16 output ----------------
__global__ __launch_bounds__(256) void ln_k(const float* __restrict__ x,
                                            const float* __restrict__ g,
                                            const float* __restrict__ b,
                                            ushort* __restrict__ xn_b) {
  __shared__ float red[8];
  int row = blockIdx.x;
  const float4* xr = (const float4*)(x + (size_t)row * DM);
  float4 v = xr[threadIdx.x];
  float s = v.x + v.y + v.z + v.w;
#pragma unroll
  for (int o = 32; o > 0; o >>= 1) s += __shfl_down(s, o, 64);
  int lane = threadIdx.x & 63, w = threadIdx.x >> 6;
  if (lane == 0) red[w] = s;
  __syncthreads();
  float mu = (red[0] + red[1] + red[2] + red[3]) * (1.0f / DM);
  float dx = v.x - mu, dy = v.y - mu, dz = v.z - mu, dw = v.w - mu;
  float ss = dx * dx + dy * dy + dz * dz + dw * dw;
#pragma unroll
  for (int o = 32; o > 0; o >>= 1) ss += __shfl_down(ss, o, 64);
  if (lane == 0) red[4 + w] = ss;
  __syncthreads();
  float var = (red[4] + red[5] + red[6] + red[7]) * (1.0f / DM);
  float rstd = rsqrtf(var + EPSF);
  float4 gg = ((const float4*)g)[threadIdx.x];
  float4 bb = ((const float4*)b)[threadIdx.x];
  ushort4 o4;
  o4.x = f2bf(dx * rstd * gg.x + bb.x);
  o4.y = f2bf(dy * rstd * gg.y + bb.y);
  o4.z = f2bf(dz * rstd * gg.z + bb.z);
  o4.w = f2bf(dw * rstd * gg.w + bb.w);
  ((ushort4*)(xn_b + (size_t)row * DM))[threadIdx.x] = o4;
}

// ---------------- gate row-mean normalize (post-sigmoid, fp32) ------------
__global__ __launch_bounds__(256) void gatenorm_k(float* __restrict__ gate) {
  __shared__ float red[4];
  int row = blockIdx.x;
  float4* gr = (float4*)(gate + (size_t)row * DM);
  float4 v = gr[threadIdx.x];
  float s = v.x + v.y + v.z + v.w;
#pragma unroll
  for (int o = 32; o > 0; o >>= 1) s += __shfl_down(s, o, 64);
  int lane = threadIdx.x & 63, w = threadIdx.x >> 6;
  if (lane == 0) red[w] = s;
  __syncthreads();
  float mean = (red[0] + red[1] + red[2] + red[3]) * (1.0f / DM);
  float inv = 1.0f / (mean + EPSF);
  v.x *= inv; v.y *= inv; v.z *= inv; v.w *= inv;
  gr[threadIdx.x] = v;
}

// ---------------- bf16 MFMA GEMM: C = A @ Wt^T + bias (fp32 out) ---------
// mode 0: plain. mode 2: sigmoid.
#define BM 128
#define BN 128
#define BK 64
__global__ __launch_bounds__(256) void gemm_bf16_k(
    const ushort* __restrict__ A, const ushort* __restrict__ Bt,
    const float* __restrict__ bias, float* __restrict__ C, int ldc,
    int K, int mode) {
  __shared__ __align__(16) ushort As[BM * BK];
  __shared__ __align__(16) ushort Bs[BN * BK];
  int tid = threadIdx.x, lane = tid & 63, w = tid >> 6;
  int m0 = blockIdx.y * BM, n0 = blockIdx.x * BN;
  int wr = w >> 1, wc = w & 1;
  f32x4 acc[4][4] = {};
  for (int k0 = 0; k0 < K; k0 += BK) {
#pragma unroll
    for (int j = 0; j < 4; j++) {
      int lu = (w * 4 + j) * 64 + lane;
      int r = lu >> 3;
      int kb = (lu & 7) ^ (r & 7);
      gload_lds16(A + (size_t)(m0 + r) * K + k0 + kb * 8, &As[(w * 4 + j) * 512]);
      gload_lds16(Bt + (size_t)(n0 + r) * K + k0 + kb * 8, &Bs[(w * 4 + j) * 512]);
    }
    __syncthreads();
#pragma unroll
    for (int ks = 0; ks < 2; ks++) {
      short8 af[4], bfr[4];
      int kq = ks * 4 + (lane >> 4);
#pragma unroll
      for (int f = 0; f < 4; f++) {
        int ra = wr * 64 + f * 16 + (lane & 15);
        af[f] = *(const short8*)&As[(ra * 8 + (kq ^ (ra & 7))) * 8];
        int rb = wc * 64 + f * 16 + (lane & 15);
        bfr[f] = *(const short8*)&Bs[(rb * 8 + (kq ^ (rb & 7))) * 8];
      }
#pragma unroll
      for (int i = 0; i < 4; i++)
#pragma unroll
        for (int j2 = 0; j2 < 4; j2++)
          acc[i][j2] = __builtin_amdgcn_mfma_f32_16x16x32_bf16(af[i], bfr[j2], acc[i][j2], 0, 0, 0);
    }
    __syncthreads();
  }
#pragma unroll
  for (int i = 0; i < 4; i++) {
#pragma unroll
    for (int j2 = 0; j2 < 4; j2++) {
      int col = n0 + wc * 64 + j2 * 16 + (lane & 15);
      float bv = bias[col];
#pragma unroll
      for (int r = 0; r < 4; r++) {
        int row = m0 + wr * 64 + i * 16 + (lane >> 4) * 4 + r;
        float v = acc[i][j2][r] + bv;
        if (mode == 2) v = 1.0f / (1.0f + expf(-v));
        C[(size_t)row * ldc + col] = v;
      }
    }
  }
}

// ---------------- qkv GEMM: writes bf16 qb/kb (row-major) + kt/vt (d-major)
// q,k epilogue: *gate, relu^2 + eps. v: plain.
__global__ __launch_bounds__(256) void gemm_qkv_k(
    const ushort* __restrict__ A, const ushort* __restrict__ Bt,
    const float* __restrict__ bias, const float* __restrict__ gate,
    ushort* __restrict__ qb, ushort* __restrict__ kb,
    ushort* __restrict__ kt, ushort* __restrict__ vt, int K) {
  __shared__ __align__(16) ushort As[BM * BK];
  __shared__ __align__(16) ushort Bs[BN * BK];
  int tid = threadIdx.x, lane = tid & 63, w = tid >> 6;
  int m0 = blockIdx.y * BM, n0 = blockIdx.x * BN;
  int wr = w >> 1, wc = w & 1;
  f32x4 acc[4][4] = {};
  for (int k0 = 0; k0 < K; k0 += BK) {
#pragma unroll
    for (int j = 0; j < 4; j++) {
      int lu = (w * 4 + j) * 64 + lane;
      int r = lu >> 3;
      int kb2 = (lu & 7) ^ (r & 7);
      gload_lds16(A + (size_t)(m0 + r) * K + k0 + kb2 * 8, &As[(w * 4 + j) * 512]);
      gload_lds16(Bt + (size_t)(n0 + r) * K + k0 + kb2 * 8, &Bs[(w * 4 + j) * 512]);
    }
    __syncthreads();
#pragma unroll
    for (int ks = 0; ks < 2; ks++) {
      short8 af[4], bfr[4];
      int kq = ks * 4 + (lane >> 4);
#pragma unroll
      for (int f = 0; f < 4; f++) {
        int ra = wr * 64 + f * 16 + (lane & 15);
        af[f] = *(const short8*)&As[(ra * 8 + (kq ^ (ra & 7))) * 8];
        int rb = wc * 64 + f * 16 + (lane & 15);
        bfr[f] = *(const short8*)&Bs[(rb * 8 + (kq ^ (rb & 7))) * 8];
      }
#pragma unroll
      for (int i = 0; i < 4; i++)
#pragma unroll
        for (int j2 = 0; j2 < 4; j2++)
          acc[i][j2] = __builtin_amdgcn_mfma_f32_16x16x32_bf16(af[i], bfr[j2], acc[i][j2], 0, 0, 0);
    }
    __syncthreads();
  }
#pragma unroll
  for (int i = 0; i < 4; i++) {
#pragma unroll
    for (int j2 = 0; j2 < 4; j2++) {
      int col = n0 + wc * 64 + j2 * 16 + (lane & 15);
      float bv = bias[col];
      int dreg = col & 1023;
      int h2 = dreg >> 6, dk = dreg & 63;
      int row0r = m0 + wr * 64 + i * 16 + (lane >> 4) * 4;
      int b2 = row0r >> 11;
      int tl0 = row0r & 2047;
      size_t bh2 = (size_t)b2 * 16 + h2;
      ushort pk4[4];
      if (col < 2048) {
#pragma unroll
        for (int r = 0; r < 4; r++) {
          int row = row0r + r;
          float v = acc[i][j2][r] + bv;
          float gv = gate[(size_t)row * DM + dreg];
          v *= gv;
          v = fmaxf(v, 0.0f);
          v = v * v + EPSF;
          ushort uv = f2bf(v);
          pk4[r] = uv;
          if (col < 1024) qb[(bh2 * 2048 + tl0 + r) * 64 + dk] = uv;
          else           kb[(bh2 * 2048 + tl0 + r) * 64 + dk] = uv;
        }
        if (col >= 1024) {
          uint2 p;
          p.x = pk4[0] | ((unsigned)pk4[1] << 16);
          p.y = pk4[2] | ((unsigned)pk4[3] << 16);
          *(uint2*)&kt[(bh2 * 64 + dk) * 2048 + tl0] = p;
        }
      } else {
#pragma unroll
        for (int r = 0; r < 4; r++) pk4[r] = f2bf(acc[i][j2][r] + bv);
        uint2 p;
        p.x = pk4[0] | ((unsigned)pk4[1] << 16);
        p.y = pk4[2] | ((unsigned)pk4[3] << 16);
        *(uint2*)&vt[(bh2 * 64 + dk) * 2048 + tl0] = p;
      }
    }
  }
}

// ---------------- pass 1: KVt[dv][dk] = sum_t vt[dv][t]*kt[dk][t], + ksum --
// grid (32 c, 64 bh), 256 thr. MFMA, operands direct from global.
__global__ __launch_bounds__(256) void chunkkv_k(const ushort* __restrict__ kt,
                                                 const ushort* __restrict__ vt,
                                                 float* __restrict__ KVt,
                                                 float* __restrict__ ksum) {
  int c = blockIdx.x, bh = blockIdx.y;
  const ushort* kT = kt + (size_t)bh * 64 * 2048 + (size_t)c * 64;
  const ushort* vT = vt + (size_t)bh * 64 * 2048 + (size_t)c * 64;
  __shared__ float ksp[4][64];
  int tid = threadIdx.x, l = tid & 63, w = tid >> 6;
  int lr = l & 15, lg = l >> 4;
  f32x4 acc[4] = {};
#pragma unroll
  for (int g = 0; g < 2; g++) {
    short8 a = *(const short8*)&vT[(size_t)(w * 16 + lr) * 2048 + g * 32 + lg * 8];
#pragma unroll
    for (int n = 0; n < 4; n++) {
      short8 bk = *(const short8*)&kT[(size_t)(n * 16 + lr) * 2048 + g * 32 + lg * 8];
      acc[n] = __builtin_amdgcn_mfma_f32_16x16x32_bf16(a, bk, acc[n], 0, 0, 0);
    }
  }
  float* dst = KVt + ((size_t)bh * 32 + c) * 4096;
#pragma unroll
  for (int n = 0; n < 4; n++)
#pragma unroll
    for (int r = 0; r < 4; r++)
      dst[(w * 16 + lg * 4 + r) * 64 + n * 16 + lr] = acc[n][r];
  // ksum[dk] = sum_t kt[dk][t] over this chunk
  float s = 0.0f;
  const ushort* kr = &kT[(size_t)l * 2048 + w * 16];
#pragma unroll
  for (int j = 0; j < 16; j++) s += bf2f(kr[j]);
  ksp[w][l] = s;
  __syncthreads();
  if (tid < 64)
    ksum[((size_t)bh * 32 + c) * 64 + tid] = ksp[0][tid] + ksp[1][tid] + ksp[2][tid] + ksp[3][tid];
}

// ---------------- pass 2: exclusive prefix; KV -> bf16, ksum in place -----
__global__ __launch_bounds__(256) void prefix_k(const float* __restrict__ KVt,
                                                ushort* __restrict__ KVb,
                                                float* __restrict__ ksum) {
  int bh = blockIdx.x;
  int gid = blockIdx.y * 256 + threadIdx.x;
  float run = 0.0f;
  if (gid < 4096) {
    for (int c2 = 0; c2 < 32; c2++) {
      size_t idx = ((size_t)bh * 32 + c2) * 4096 + gid;
      float v = KVt[idx];
      KVb[idx] = f2bf(run);
      run += v;
    }
  } else if (gid < 4160) {
    int d = gid - 4096;
    for (int c2 = 0; c2 < 32; c2++) {
      size_t idx = ((size_t)bh * 32 + c2) * 64 + d;
      float v = ksum[idx];
      ksum[idx] = run;
      run += v;
    }
  }
}

// ---------------- pass 3: O^T[dv][t] = KVb·Q + vt·S, S^T = mfma(K,Q) ------
// grid (32 c, 64 bh), 256 thr. SL: XOR-swizzled bf16 S^T tile (t-major).
__global__ __launch_bounds__(256) void attn_k(
    const ushort* __restrict__ qb, const ushort* __restrict__ kb,
    const ushort* __restrict__ vt, const ushort* __restrict__ KVb,
    const float* __restrict__ ks, ushort* __restrict__ attnout) {
  int c = blockIdx.x, bh = blockIdx.y;
  int b = bh >> 4, h = bh & 15;
  const ushort* qB = qb + ((size_t)bh * 2048 + (size_t)c * 64) * 64;  // [t][d]
  const ushort* kB = kb + ((size_t)bh * 2048 + (size_t)c * 64) * 64;  // [s][d]
  const ushort* vT = vt + (size_t)bh * 64 * 2048 + (size_t)c * 64;    // [dv][t-global]
  const ushort* kvB = KVb + ((size_t)bh * 32 + c) * 4096;             // [dv][dk]
  const float* ksP = ks + ((size_t)bh * 32 + c) * 64;
  __shared__ __align__(16) char SL[64 * 128];  // S^T bf16, [t][s] swizzled
  __shared__ float denp[4][64];
  __shared__ float den2p[4][64];
  __shared__ float invden[64];
  int tid = threadIdx.x, l = tid & 63, w = tid >> 6;
  int lr = l & 15, lg = l >> 4;
  // state part of denominator: den2[t] = q[t] . ks   (wave w covers d-slice)
  {
    float d2 = 0.0f;
    const ushort* qr = &qB[(size_t)l * 64 + w * 16];
#pragma unroll
    for (int j = 0; j < 16; j++) d2 += bf2f(qr[j]) * ksP[w * 16 + j];
    den2p[w][l] = d2;
  }
  // phase A: S^T tiles (wave w -> s-block w), mask, den rowsum, SL write
#pragma unroll
  for (int n = 0; n < 4; n++) {
    f32x4 sa = {0.f, 0.f, 0.f, 0.f};
#pragma unroll
    for (int g = 0; g < 2; g++) {
      short8 a = *(const short8*)&kB[(size_t)(w * 16 + lr) * 64 + g * 32 + lg * 8];
      short8 bq = *(const short8*)&qB[(size_t)(n * 16 + lr) * 64 + g * 32 + lg * 8];
      sa = __builtin_amdgcn_mfma_f32_16x16x32_bf16(a, bq, sa, 0, 0, 0);
    }
    int t = n * 16 + lr;       // acc col
    int s0 = w * 16 + lg * 4;  // acc rows s0..s0+3
    float dsum = 0.0f;
    ushort sb[4];
#pragma unroll
    for (int r = 0; r < 4; r++) {
      float v = (s0 + r <= t) ? sa[r] : 0.0f;
      dsum += v;
      sb[r] = f2bf(v);
    }
    dsum += __shfl_xor(dsum, 16, 64);
    dsum += __shfl_xor(dsum, 32, 64);
    if (l < 16) denp[w][n * 16 + l] = dsum;
    int u = (s0 >> 3) ^ (t & 7);
    uint2 p;
    p.x = sb[0] | ((unsigned)sb[1] << 16);
    p.y = sb[2] | ((unsigned)sb[3] << 16);
    *(uint2*)&SL[t * 128 + u * 16 + (s0 & 7) * 2] = p;
  }
  __syncthreads();
  if (tid < 64) {
    float den = denp[0][tid] + denp[1][tid] + denp[2][tid] + denp[3][tid] +
                den2p[0][tid] + den2p[1][tid] + den2p[2][tid] + den2p[3][tid] + EPSF;
    invden[tid] = 1.0f / den;
  }
  __syncthreads();
  // phase B: O^T tiles (wave w -> dv-block w)
#pragma unroll
  for (int n = 0; n < 4; n++) {
    f32x4 oa = {0.f, 0.f, 0.f, 0.f};
#pragma unroll
    for (int g = 0; g < 2; g++) {  // O1: KV-prefix . Q
      short8 a = *(const short8*)&kvB[(size_t)(w * 16 + lr) * 64 + g * 32 + lg * 8];
      short8 bq = *(const short8*)&qB[(size_t)(n * 16 + lr) * 64 + g * 32 + lg * 8];
      oa = __builtin_amdgcn_mfma_f32_16x16x32_bf16(a, bq, oa, 0, 0, 0);
    }
    int t = n * 16 + lr;
#pragma unroll
    for (int g = 0; g < 2; g++) {  // O2: V . S
      short8 a = *(const short8*)&vT[(size_t)(w * 16 + lr) * 2048 + g * 32 + lg * 8];
      int u = (g * 4 + lg) ^ (t & 7);
      short8 bs = *(const short8*)&SL[t * 128 + u * 16];
      oa = __builtin_amdgcn_mfma_f32_16x16x32_bf16(a, bs, oa, 0, 0, 0);
    }
    float iv = invden[t];
    ushort ob[4];
#pragma unroll
    for (int r = 0; r < 4; r++) ob[r] = f2bf(oa[r] * iv);
    size_t tok = (size_t)b * 2048 + (size_t)c * 64 + t;
    uint2 p;
    p.x = ob[0] | ((unsigned)ob[1] << 16);
    p.y = ob[2] | ((unsigned)ob[3] << 16);
    *(uint2*)&attnout[tok * 1024 + h * 64 + w * 16 + lg * 4] = p;
  }
}

extern "C" void kernel_launch(void* const* d_in, const int* in_sizes, int n_in,
                              void* d_out, int out_size, void* d_ws, size_t ws_size,
                              hipStream_t stream) {
  const float* x      = (const float*)d_in[0];
  const float* ln_g   = (const float*)d_in[1];
  const float* ln_b   = (const float*)d_in[2];
  const float* W_qkv  = (const float*)d_in[3];
  const float* b_qkv  = (const float*)d_in[4];
  const float* W_gate = (const float*)d_in[5];
  const float* b_gate = (const float*)d_in[6];
  const float* W_proj = (const float*)d_in[7];
  const float* b_proj = (const float*)d_in[8];
  float* out = (float*)d_out;

  // Workspace: 10 slots of TD*2 bytes = 167.77 MB (same peak as round 2).
  char* wsb = (char*)d_ws;
  const size_t TD = (size_t)TOK * DM;
  const size_t SLOT = TD * 2;
  ushort* x_b     = (ushort*)(wsb + 0 * SLOT);  // dead after gate GEMM
  ushort* attnout = (ushort*)(wsb + 0 * SLOT);
  ushort* xn_b    = (ushort*)(wsb + 1 * SLOT);
  ushort* qb      = (ushort*)(wsb + 2 * SLOT);
  ushort* kb      = (ushort*)(wsb + 3 * SLOT);
  ushort* kt      = (ushort*)(wsb + 4 * SLOT);
  ushort* vt      = (ushort*)(wsb + 5 * SLOT);
  float*  gate    = (float*)(wsb + 6 * SLOT);   // slots 6-7; dead after qkv GEMM
  float*  KVt     = (float*)(wsb + 6 * SLOT);   // slots 6-7
  ushort* Wt_gate = (ushort*)(wsb + 8 * SLOT);  // dead after gate GEMM
  ushort* Wt_qkv  = (ushort*)(wsb + 8 * SLOT);  // dead after qkv GEMM
  ushort* KVb     = (ushort*)(wsb + 8 * SLOT);
  ushort* Wt_proj = (ushort*)(wsb + 9 * SLOT);
  float*  ksum    = (float*)(wsb + 9 * SLOT + 8 * 1024 * 1024);

  // 1) x -> bf16
  cvt_k<<<8192, 256, 0, stream>>>(x, x_b, (int)(TD / 4));
  // 2) W_gate -> transposed bf16
  tconv_k<<<dim3(DM / 32, DM / 32), 256, 0, stream>>>(W_gate, Wt_gate, DM, DM);
  // 3) gate = sigmoid(x @ W_gate + b_gate), fp32
  gemm_bf16_k<<<dim3(DM / BN, TOK / BM), 256, 0, stream>>>(x_b, Wt_gate, b_gate, gate, DM, DM, 2);
  // 4) gate /= (row-mean + eps)
  gatenorm_k<<<TOK, 256, 0, stream>>>(gate);
  // 5) LayerNorm -> bf16
  ln_k<<<TOK, 256, 0, stream>>>(x, ln_g, ln_b, xn_b);
  // 6) W_qkv -> transposed bf16 (x_b dead region is slot0; Wt_qkv in slot8)
  tconv_k<<<dim3(3 * DM / 32, DM / 32), 256, 0, stream>>>(W_qkv, Wt_qkv, DM, 3 * DM);
  // 7) qkv GEMM -> qb/kb (row-major) + kt/vt (d-major), bf16, fused gate+relu^2
  gemm_qkv_k<<<dim3(3 * DM / BN, TOK / BM), 256, 0, stream>>>(xn_b, Wt_qkv, b_qkv, gate,
                                                              qb, kb, kt, vt, DM);
  // 8) per-chunk KV^T + ksum (gate dead -> KVt)
  chunkkv_k<<<dim3(32, 64), 256, 0, stream>>>(kt, vt, KVt, ksum);
  // 9) W_proj -> transposed bf16
  tconv_k<<<dim3(DM / 32, DM / 32), 256, 0, stream>>>(W_proj, Wt_proj, DM, DM);
  // 10) exclusive chunk prefix: KVt fp32 -> KVb bf16 (slot8), ksum in place
  prefix_k<<<dim3(64, 17), 256, 0, stream>>>(KVt, KVb, ksum);
  // 11) chunk outputs -> attnout bf16 row-major (slot0)
  attn_k<<<dim3(32, 64), 256, 0, stream>>>(qb, kb, vt, KVb, ksum, attnout);
  // 12) out = attn @ W_proj + b_proj
  gemm_bf16_k<<<dim3(DM / BN, TOK / BM), 256, 0, stream>>>(attnout, Wt_proj, b_proj, out, DM, DM, 0);
}

// Round 4
// 216.469 us; speedup vs baseline: 7.2245x; 1.0859x over previous
//
#include <hip/hip_runtime.h>
#include <math.h>

#define TOK 8192
#define DM 1024
#define EPSF 1e-5f

typedef __attribute__((ext_vector_type(8))) short short8;
typedef __attribute__((ext_vector_type(4))) float f32x4;

static __device__ __forceinline__ ushort f2bf(float f) {
  unsigned u = __float_as_uint(f);
  unsigned r = (u + 0x7fffu + ((u >> 16) & 1u)) >> 16;
  return (ushort)r;
}
static __device__ __forceinline__ float bf2f(ushort u) {
  return __uint_as_float((unsigned)u << 16);
}

static __device__ __forceinline__ void gload_lds16(const ushort* g, ushort* l) {
  __builtin_amdgcn_global_load_lds((const __attribute__((address_space(1))) void*)g,
                                   (__attribute__((address_space(3))) void*)l, 16, 0, 0);
}

// bank-aware swizzle for the C-staging tile (stride 128 ushorts = 256B):
// varies bank bits with row%8 AND row/8 so both row-reads and stride-8
// column-reads (kt/vt transpose) stay spread.
static __device__ __forceinline__ int cswz(int row) {
  return (((row & 7) ^ ((row >> 3) & 7)) << 3);
}

// ---------------- fused LayerNorm + x->bf16 ----------------
__global__ __launch_bounds__(256) void lncvt_k(const float* __restrict__ x,
                                               const float* __restrict__ g,
                                               const float* __restrict__ b,
                                               ushort* __restrict__ x_b,
                                               ushort* __restrict__ xn_b) {
  __shared__ float red[8];
  int row = blockIdx.x;
  const float4* xr = (const float4*)(x + (size_t)row * DM);
  float4 v = xr[threadIdx.x];
  ushort4 xb4;
  xb4.x = f2bf(v.x); xb4.y = f2bf(v.y); xb4.z = f2bf(v.z); xb4.w = f2bf(v.w);
  ((ushort4*)(x_b + (size_t)row * DM))[threadIdx.x] = xb4;
  float s = v.x + v.y + v.z + v.w;
#pragma unroll
  for (int o = 32; o > 0; o >>= 1) s += __shfl_down(s, o, 64);
  int lane = threadIdx.x & 63, w = threadIdx.x >> 6;
  if (lane == 0) red[w] = s;
  __syncthreads();
  float mu = (red[0] + red[1] + red[2] + red[3]) * (1.0f / DM);
  float dx = v.x - mu, dy = v.y - mu, dz = v.z - mu, dw = v.w - mu;
  float ss = dx * dx + dy * dy + dz * dz + dw * dw;
#pragma unroll
  for (int o = 32; o > 0; o >>= 1) ss += __shfl_down(ss, o, 64);
  if (lane == 0) red[4 + w] = ss;
  __syncthreads();
  float var = (red[4] + red[5] + red[6] + red[7]) * (1.0f / DM);
  float rstd = rsqrtf(var + EPSF);
  float4 gg = ((const float4*)g)[threadIdx.x];
  float4 bb = ((const float4*)b)[threadIdx.x];
  ushort4 o4;
  o4.x = f2bf(dx * rstd * gg.x + bb.x);
  o4.y = f2bf(dy * rstd * gg.y + bb.y);
  o4.z = f2bf(dz * rstd * gg.z + bb.z);
  o4.w = f2bf(dw * rstd * gg.w + bb.w);
  ((ushort4*)(xn_b + (size_t)row * DM))[threadIdx.x] = o4;
}

// ---------------- W [K][N] fp32 -> Wt [N][K] bf16 ----------------
__global__ __launch_bounds__(256) void tconv_k(const float* __restrict__ W,
                                               ushort* __restrict__ Wt, int K, int N) {
  __shared__ ushort tile[32][33];
  int k0 = blockIdx.y * 32, n0 = blockIdx.x * 32;
  int tx = threadIdx.x & 31, ty = threadIdx.x >> 5;
#pragma unroll
  for (int i = 0; i < 4; i++) {
    int k = ty + i * 8;
    tile[k][tx] = f2bf(W[(size_t)(k0 + k) * N + n0 + tx]);
  }
  __syncthreads();
#pragma unroll
  for (int i = 0; i < 4; i++) {
    int n = ty + i * 8;
    Wt[(size_t)(n0 + n) * K + k0 + tx] = tile[tx][n];
  }
}

// ---------------- gate row-mean normalize, bf16 in/out ----------------
__global__ __launch_bounds__(256) void gatenorm_b_k(ushort* __restrict__ gate_b) {
  __shared__ float red[4];
  int row = blockIdx.x;
  ushort4* gr = (ushort4*)(gate_b + (size_t)row * DM);
  ushort4 u4 = gr[threadIdx.x];
  float v0 = bf2f(u4.x), v1 = bf2f(u4.y), v2 = bf2f(u4.z), v3 = bf2f(u4.w);
  float s = v0 + v1 + v2 + v3;
#pragma unroll
  for (int o = 32; o > 0; o >>= 1) s += __shfl_down(s, o, 64);
  int lane = threadIdx.x & 63, w = threadIdx.x >> 6;
  if (lane == 0) red[w] = s;
  __syncthreads();
  float mean = (red[0] + red[1] + red[2] + red[3]) * (1.0f / DM);
  float inv = 1.0f / (mean + EPSF);
  u4.x = f2bf(v0 * inv); u4.y = f2bf(v1 * inv);
  u4.z = f2bf(v2 * inv); u4.w = f2bf(v3 * inv);
  gr[threadIdx.x] = u4;
}

// ---------------- bf16 MFMA GEMM: C = A @ Wt^T + bias ----------------
// mode 0: fp32 out (Cf). mode 2: sigmoid -> bf16 out (Cb).
#define BM 128
#define BN 128
#define BK 64
__global__ __launch_bounds__(256) void gemm_bf16_k(
    const ushort* __restrict__ A, const ushort* __restrict__ Bt,
    const float* __restrict__ bias, float* __restrict__ Cf,
    ushort* __restrict__ Cb, int ldc, int K, int mode) {
  __shared__ __align__(16) ushort As[BM * BK];
  __shared__ __align__(16) ushort Bs[BN * BK];
  int tid = threadIdx.x, lane = tid & 63, w = tid >> 6;
  int m0 = blockIdx.y * BM, n0 = blockIdx.x * BN;
  int wr = w >> 1, wc = w & 1;
  f32x4 acc[4][4] = {};
  for (int k0 = 0; k0 < K; k0 += BK) {
#pragma unroll
    for (int j = 0; j < 4; j++) {
      int lu = (w * 4 + j) * 64 + lane;
      int r = lu >> 3;
      int kb = (lu & 7) ^ (r & 7);
      gload_lds16(A + (size_t)(m0 + r) * K + k0 + kb * 8, &As[(w * 4 + j) * 512]);
      gload_lds16(Bt + (size_t)(n0 + r) * K + k0 + kb * 8, &Bs[(w * 4 + j) * 512]);
    }
    __syncthreads();
#pragma unroll
    for (int ks = 0; ks < 2; ks++) {
      short8 af[4], bfr[4];
      int kq = ks * 4 + (lane >> 4);
#pragma unroll
      for (int f = 0; f < 4; f++) {
        int ra = wr * 64 + f * 16 + (lane & 15);
        af[f] = *(const short8*)&As[(ra * 8 + (kq ^ (ra & 7))) * 8];
        int rb = wc * 64 + f * 16 + (lane & 15);
        bfr[f] = *(const short8*)&Bs[(rb * 8 + (kq ^ (rb & 7))) * 8];
      }
#pragma unroll
      for (int i = 0; i < 4; i++)
#pragma unroll
        for (int j2 = 0; j2 < 4; j2++)
          acc[i][j2] = __builtin_amdgcn_mfma_f32_16x16x32_bf16(af[i], bfr[j2], acc[i][j2], 0, 0, 0);
    }
    __syncthreads();
  }
#pragma unroll
  for (int i = 0; i < 4; i++) {
#pragma unroll
    for (int j2 = 0; j2 < 4; j2++) {
      int col = n0 + wc * 64 + j2 * 16 + (lane & 15);
      float bv = bias[col];
#pragma unroll
      for (int r = 0; r < 4; r++) {
        int row = m0 + wr * 64 + i * 16 + (lane >> 4) * 4 + r;
        float v = acc[i][j2][r] + bv;
        if (mode == 2) {
          v = 1.0f / (1.0f + expf(-v));
          Cb[(size_t)row * ldc + col] = f2bf(v);
        } else {
          Cf[(size_t)row * ldc + col] = v;
        }
      }
    }
  }
}

// ---------------- qkv GEMM with LDS-staged coalesced epilogue ------------
// Writes qb/kb (row-major [bh][t][64]) and kt/vt (d-major [bh][64][2048]).
// q,k: *gate(bf16), relu^2 + eps. v: plain.
__global__ __launch_bounds__(256) void gemm_qkv_k(
    const ushort* __restrict__ A, const ushort* __restrict__ Bt,
    const float* __restrict__ bias, const ushort* __restrict__ gate_b,
    ushort* __restrict__ qb, ushort* __restrict__ kb,
    ushort* __restrict__ kt, ushort* __restrict__ vt, int K) {
  __shared__ __align__(16) ushort sh[16896];  // As|Bs during K-loop; gate/C tile after
  ushort* As = sh;
  ushort* Bs = sh + BM * BK;
  int tid = threadIdx.x, lane = tid & 63, w = tid >> 6;
  int m0 = blockIdx.y * BM, n0 = blockIdx.x * BN;
  int wr = w >> 1, wc = w & 1;
  f32x4 acc[4][4] = {};
  for (int k0 = 0; k0 < K; k0 += BK) {
#pragma unroll
    for (int j = 0; j < 4; j++) {
      int lu = (w * 4 + j) * 64 + lane;
      int r = lu >> 3;
      int kb2 = (lu & 7) ^ (r & 7);
      gload_lds16(A + (size_t)(m0 + r) * K + k0 + kb2 * 8, &As[(w * 4 + j) * 512]);
      gload_lds16(Bt + (size_t)(n0 + r) * K + k0 + kb2 * 8, &Bs[(w * 4 + j) * 512]);
    }
    __syncthreads();
#pragma unroll
    for (int ks = 0; ks < 2; ks++) {
      short8 af[4], bfr[4];
      int kq = ks * 4 + (lane >> 4);
#pragma unroll
      for (int f = 0; f < 4; f++) {
        int ra = wr * 64 + f * 16 + (lane & 15);
        af[f] = *(const short8*)&As[(ra * 8 + (kq ^ (ra & 7))) * 8];
        int rb = wc * 64 + f * 16 + (lane & 15);
        bfr[f] = *(const short8*)&Bs[(rb * 8 + (kq ^ (rb & 7))) * 8];
      }
#pragma unroll
      for (int i = 0; i < 4; i++)
#pragma unroll
        for (int j2 = 0; j2 < 4; j2++)
          acc[i][j2] = __builtin_amdgcn_mfma_f32_16x16x32_bf16(af[i], bfr[j2], acc[i][j2], 0, 0, 0);
    }
    __syncthreads();
  }
  // ---- epilogue ----
  int region = n0 >> 10;     // 0=q, 1=k, 2=v (BN=128 divides 1024)
  int n0b = n0 & 1023;
  int h0 = n0b >> 6;
  if (region < 2) {
    // stage gate tile (plain layout, stride 132 to de-conflict reads)
#pragma unroll
    for (int it = 0; it < 8; it++) {
      int e = it * 256 + tid;
      int row = e >> 4, ch = e & 15;
      *(short8*)&sh[row * 132 + ch * 8] =
          *(const short8*)&gate_b[(size_t)(m0 + row) * DM + n0b + ch * 8];
    }
    __syncthreads();
#pragma unroll
    for (int i = 0; i < 4; i++) {
#pragma unroll
      for (int j2 = 0; j2 < 4; j2++) {
        int cl = wc * 64 + j2 * 16 + (lane & 15);
        float bv = bias[n0 + cl];
        int rl0 = wr * 64 + i * 16 + (lane >> 4) * 4;
#pragma unroll
        for (int r = 0; r < 4; r++) {
          float gv = bf2f(sh[(rl0 + r) * 132 + cl]);
          float v = (acc[i][j2][r] + bv) * gv;
          v = fmaxf(v, 0.0f);
          acc[i][j2][r] = v * v + EPSF;
        }
      }
    }
    __syncthreads();
  } else {
#pragma unroll
    for (int i = 0; i < 4; i++)
#pragma unroll
      for (int j2 = 0; j2 < 4; j2++) {
        int cl = wc * 64 + j2 * 16 + (lane & 15);
        float bv = bias[n0 + cl];
#pragma unroll
        for (int r = 0; r < 4; r++) acc[i][j2][r] += bv;
      }
  }
  // pack C tile into LDS, swizzled
#pragma unroll
  for (int i = 0; i < 4; i++) {
#pragma unroll
    for (int j2 = 0; j2 < 4; j2++) {
      int cl = wc * 64 + j2 * 16 + (lane & 15);
      int rl0 = wr * 64 + i * 16 + (lane >> 4) * 4;
#pragma unroll
      for (int r = 0; r < 4; r++) {
        int row = rl0 + r;
        sh[row * 128 + (cl ^ cswz(row))] = f2bf(acc[i][j2][r]);
      }
    }
  }
  __syncthreads();
  // coalesced stores
  if (region < 2) {
    ushort* dstRM = (region == 0) ? qb : kb;
#pragma unroll
    for (int it = 0; it < 8; it++) {
      int e = it * 256 + tid;
      int row = e >> 4, ch = e & 15;
      short8 val = *(const short8*)&sh[row * 128 + ((ch * 8) ^ cswz(row))];
      int tglob = m0 + row;
      size_t bh2 = (size_t)(tglob >> 11) * 16 + h0 + (ch >> 3);
      *(short8*)&dstRM[(bh2 * 2048 + (tglob & 2047)) * 64 + (ch & 7) * 8] = val;
    }
  }
  if (region >= 1) {
    ushort* dstT = (region == 1) ? kt : vt;
#pragma unroll
    for (int it = 0; it < 8; it++) {
      int e = it * 256 + tid;
      int tch = e & 15, dkrow = e >> 4;
      short8 val;
#pragma unroll
      for (int j = 0; j < 8; j++) {
        int row = tch * 8 + j;
        val[j] = (short)sh[row * 128 + (dkrow ^ cswz(row))];
      }
      int tglob0 = m0 + tch * 8;
      size_t bh2 = (size_t)(tglob0 >> 11) * 16 + h0 + (dkrow >> 6);
      *(short8*)&dstT[(bh2 * 64 + (dkrow & 63)) * 2048 + (tglob0 & 2047)] = val;
    }
  }
}

// ---------------- pass 1: KVt[dv][dk] = sum_t vt[dv][t]*kt[dk][t], + ksum --
__global__ __launch_bounds__(256) void chunkkv_k(const ushort* __restrict__ kt,
                                                 const ushort* __restrict__ vt,
                                                 float* __restrict__ KVt,
                                                 float* __restrict__ ksum) {
  int c = blockIdx.x, bh = blockIdx.y;
  const ushort* kT = kt + (size_t)bh * 64 * 2048 + (size_t)c * 64;
  const ushort* vT = vt + (size_t)bh * 64 * 2048 + (size_t)c * 64;
  __shared__ float ksp[4][64];
  int tid = threadIdx.x, l = tid & 63, w = tid >> 6;
  int lr = l & 15, lg = l >> 4;
  f32x4 acc[4] = {};
#pragma unroll
  for (int g = 0; g < 2; g++) {
    short8 a = *(const short8*)&vT[(size_t)(w * 16 + lr) * 2048 + g * 32 + lg * 8];
#pragma unroll
    for (int n = 0; n < 4; n++) {
      short8 bk = *(const short8*)&kT[(size_t)(n * 16 + lr) * 2048 + g * 32 + lg * 8];
      acc[n] = __builtin_amdgcn_mfma_f32_16x16x32_bf16(a, bk, acc[n], 0, 0, 0);
    }
  }
  float* dst = KVt + ((size_t)bh * 32 + c) * 4096;
#pragma unroll
  for (int n = 0; n < 4; n++)
#pragma unroll
    for (int r = 0; r < 4; r++)
      dst[(w * 16 + lg * 4 + r) * 64 + n * 16 + lr] = acc[n][r];
  float s = 0.0f;
  const ushort* kr = &kT[(size_t)l * 2048 + w * 16];
#pragma unroll
  for (int j = 0; j < 16; j++) s += bf2f(kr[j]);
  ksp[w][l] = s;
  __syncthreads();
  if (tid < 64)
    ksum[((size_t)bh * 32 + c) * 64 + tid] = ksp[0][tid] + ksp[1][tid] + ksp[2][tid] + ksp[3][tid];
}

// ---------------- pass 2: exclusive prefix; KV -> bf16, ksum in place -----
__global__ __launch_bounds__(256) void prefix_k(const float* __restrict__ KVt,
                                                ushort* __restrict__ KVb,
                                                float* __restrict__ ksum) {
  int bh = blockIdx.x;
  int gid = blockIdx.y * 256 + threadIdx.x;
  float run = 0.0f;
  if (gid < 4096) {
    for (int c2 = 0; c2 < 32; c2++) {
      size_t idx = ((size_t)bh * 32 + c2) * 4096 + gid;
      float v = KVt[idx];
      KVb[idx] = f2bf(run);
      run += v;
    }
  } else if (gid < 4160) {
    int d = gid - 4096;
    for (int c2 = 0; c2 < 32; c2++) {
      size_t idx = ((size_t)bh * 32 + c2) * 64 + d;
      float v = ksum[idx];
      ksum[idx] = run;
      run += v;
    }
  }
}

// ---------------- pass 3: O^T[dv][t] = KVb·Q + vt·S, S^T = mfma(K,Q) ------
__global__ __launch_bounds__(256) void attn_k(
    const ushort* __restrict__ qb, const ushort* __restrict__ kb,
    const ushort* __restrict__ vt, const ushort* __restrict__ KVb,
    const float* __restrict__ ks, ushort* __restrict__ attnout) {
  int c = blockIdx.x, bh = blockIdx.y;
  int b = bh >> 4, h = bh & 15;
  const ushort* qB = qb + ((size_t)bh * 2048 + (size_t)c * 64) * 64;
  const ushort* kB = kb + ((size_t)bh * 2048 + (size_t)c * 64) * 64;
  const ushort* vT = vt + (size_t)bh * 64 * 2048 + (size_t)c * 64;
  const ushort* kvB = KVb + ((size_t)bh * 32 + c) * 4096;
  const float* ksP = ks + ((size_t)bh * 32 + c) * 64;
  __shared__ __align__(16) char SL[64 * 128];
  __shared__ float denp[4][64];
  __shared__ float den2p[4][64];
  __shared__ float invden[64];
  int tid = threadIdx.x, l = tid & 63, w = tid >> 6;
  int lr = l & 15, lg = l >> 4;
  {
    float d2 = 0.0f;
    const ushort* qr = &qB[(size_t)l * 64 + w * 16];
#pragma unroll
    for (int j = 0; j < 16; j++) d2 += bf2f(qr[j]) * ksP[w * 16 + j];
    den2p[w][l] = d2;
  }
#pragma unroll
  for (int n = 0; n < 4; n++) {
    f32x4 sa = {0.f, 0.f, 0.f, 0.f};
#pragma unroll
    for (int g = 0; g < 2; g++) {
      short8 a = *(const short8*)&kB[(size_t)(w * 16 + lr) * 64 + g * 32 + lg * 8];
      short8 bq = *(const short8*)&qB[(size_t)(n * 16 + lr) * 64 + g * 32 + lg * 8];
      sa = __builtin_amdgcn_mfma_f32_16x16x32_bf16(a, bq, sa, 0, 0, 0);
    }
    int t = n * 16 + lr;
    int s0 = w * 16 + lg * 4;
    float dsum = 0.0f;
    ushort sb[4];
#pragma unroll
    for (int r = 0; r < 4; r++) {
      float v = (s0 + r <= t) ? sa[r] : 0.0f;
      dsum += v;
      sb[r] = f2bf(v);
    }
    dsum += __shfl_xor(dsum, 16, 64);
    dsum += __shfl_xor(dsum, 32, 64);
    if (l < 16) denp[w][n * 16 + l] = dsum;
    int u = (s0 >> 3) ^ (t & 7);
    uint2 p;
    p.x = sb[0] | ((unsigned)sb[1] << 16);
    p.y = sb[2] | ((unsigned)sb[3] << 16);
    *(uint2*)&SL[t * 128 + u * 16 + (s0 & 7) * 2] = p;
  }
  __syncthreads();
  if (tid < 64) {
    float den = denp[0][tid] + denp[1][tid] + denp[2][tid] + denp[3][tid] +
                den2p[0][tid] + den2p[1][tid] + den2p[2][tid] + den2p[3][tid] + EPSF;
    invden[tid] = 1.0f / den;
  }
  __syncthreads();
#pragma unroll
  for (int n = 0; n < 4; n++) {
    f32x4 oa = {0.f, 0.f, 0.f, 0.f};
#pragma unroll
    for (int g = 0; g < 2; g++) {
      short8 a = *(const short8*)&kvB[(size_t)(w * 16 + lr) * 64 + g * 32 + lg * 8];
      short8 bq = *(const short8*)&qB[(size_t)(n * 16 + lr) * 64 + g * 32 + lg * 8];
      oa = __builtin_amdgcn_mfma_f32_16x16x32_bf16(a, bq, oa, 0, 0, 0);
    }
    int t = n * 16 + lr;
#pragma unroll
    for (int g = 0; g < 2; g++) {
      short8 a = *(const short8*)&vT[(size_t)(w * 16 + lr) * 2048 + g * 32 + lg * 8];
      int u = (g * 4 + lg) ^ (t & 7);
      short8 bs = *(const short8*)&SL[t * 128 + u * 16];
      oa = __builtin_amdgcn_mfma_f32_16x16x32_bf16(a, bs, oa, 0, 0, 0);
    }
    float iv = invden[t];
    ushort ob[4];
#pragma unroll
    for (int r = 0; r < 4; r++) ob[r] = f2bf(oa[r] * iv);
    size_t tok = (size_t)b * 2048 + (size_t)c * 64 + t;
    uint2 p;
    p.x = ob[0] | ((unsigned)ob[1] << 16);
    p.y = ob[2] | ((unsigned)ob[3] << 16);
    *(uint2*)&attnout[tok * 1024 + h * 64 + w * 16 + lg * 4] = p;
  }
}

extern "C" void kernel_launch(void* const* d_in, const int* in_sizes, int n_in,
                              void* d_out, int out_size, void* d_ws, size_t ws_size,
                              hipStream_t stream) {
  const float* x      = (const float*)d_in[0];
  const float* ln_g   = (const float*)d_in[1];
  const float* ln_b   = (const float*)d_in[2];
  const float* W_qkv  = (const float*)d_in[3];
  const float* b_qkv  = (const float*)d_in[4];
  const float* W_gate = (const float*)d_in[5];
  const float* b_gate = (const float*)d_in[6];
  const float* W_proj = (const float*)d_in[7];
  const float* b_proj = (const float*)d_in[8];
  float* out = (float*)d_out;

  char* wsb = (char*)d_ws;
  const size_t TD = (size_t)TOK * DM;
  const size_t SLOT = TD * 2;
  ushort* x_b     = (ushort*)(wsb + 0 * SLOT);  // dead after gate GEMM
  ushort* attnout = (ushort*)(wsb + 0 * SLOT);
  ushort* xn_b    = (ushort*)(wsb + 1 * SLOT);
  ushort* qb      = (ushort*)(wsb + 2 * SLOT);
  ushort* kb      = (ushort*)(wsb + 3 * SLOT);
  ushort* kt      = (ushort*)(wsb + 4 * SLOT);
  ushort* vt      = (ushort*)(wsb + 5 * SLOT);
  ushort* gate_b  = (ushort*)(wsb + 6 * SLOT);  // dead after qkv GEMM
  float*  KVt     = (float*)(wsb + 6 * SLOT);   // slots 6-7
  ushort* Wt_gate = (ushort*)(wsb + 8 * SLOT);  // dead after gate GEMM
  ushort* Wt_qkv  = (ushort*)(wsb + 8 * SLOT);  // dead after qkv GEMM
  ushort* KVb     = (ushort*)(wsb + 8 * SLOT);
  ushort* Wt_proj = (ushort*)(wsb + 9 * SLOT);
  float*  ksum    = (float*)(wsb + 9 * SLOT + 8 * 1024 * 1024);

  // 1) x -> x_b (bf16) and LayerNorm -> xn_b (bf16), one x read
  lncvt_k<<<TOK, 256, 0, stream>>>(x, ln_g, ln_b, x_b, xn_b);
  // 2) W_gate -> transposed bf16
  tconv_k<<<dim3(DM / 32, DM / 32), 256, 0, stream>>>(W_gate, Wt_gate, DM, DM);
  // 3) gate = sigmoid(x @ W_gate + b_gate) -> bf16
  gemm_bf16_k<<<dim3(DM / BN, TOK / BM), 256, 0, stream>>>(x_b, Wt_gate, b_gate, nullptr,
                                                           gate_b, DM, DM, 2);
  // 4) gate /= (row-mean + eps), bf16 in place
  gatenorm_b_k<<<TOK, 256, 0, stream>>>(gate_b);
  // 5) W_qkv -> transposed bf16
  tconv_k<<<dim3(3 * DM / 32, DM / 32), 256, 0, stream>>>(W_qkv, Wt_qkv, DM, 3 * DM);
  // 6) qkv GEMM -> qb/kb + kt/vt (bf16), fused gate+relu^2, LDS-staged stores
  gemm_qkv_k<<<dim3(3 * DM / BN, TOK / BM), 256, 0, stream>>>(xn_b, Wt_qkv, b_qkv, gate_b,
                                                              qb, kb, kt, vt, DM);
  // 7) per-chunk KV^T + ksum (gate_b dead -> KVt)
  chunkkv_k<<<dim3(32, 64), 256, 0, stream>>>(kt, vt, KVt, ksum);
  // 8) W_proj -> transposed bf16
  tconv_k<<<dim3(DM / 32, DM / 32), 256, 0, stream>>>(W_proj, Wt_proj, DM, DM);
  // 9) exclusive chunk prefix: KVt fp32 -> KVb bf16, ksum in place
  prefix_k<<<dim3(64, 17), 256, 0, stream>>>(KVt, KVb, ksum);
  // 10) chunk outputs -> attnout bf16 row-major
  attn_k<<<dim3(32, 64), 256, 0, stream>>>(qb, kb, vt, KVb, ksum, attnout);
  // 11) out = attn @ W_proj + b_proj (fp32 out)
  gemm_bf16_k<<<dim3(DM / BN, TOK / BM), 256, 0, stream>>>(attnout, Wt_proj, b_proj, out,
                                                           nullptr, DM, DM, 0);
}

// Round 5
// 211.701 us; speedup vs baseline: 7.3872x; 1.0225x over previous
//
#include <hip/hip_runtime.h>
#include <math.h>

#define TOK 8192
#define DM 1024
#define EPSF 1e-5f

typedef __attribute__((ext_vector_type(8))) short short8;
typedef __attribute__((ext_vector_type(4))) float f32x4;

static __device__ __forceinline__ ushort f2bf(float f) {
  unsigned u = __float_as_uint(f);
  unsigned r = (u + 0x7fffu + ((u >> 16) & 1u)) >> 16;
  return (ushort)r;
}
static __device__ __forceinline__ float bf2f(ushort u) {
  return __uint_as_float((unsigned)u << 16);
}

static __device__ __forceinline__ void gload_lds16(const ushort* g, ushort* l) {
  __builtin_amdgcn_global_load_lds((const __attribute__((address_space(1))) void*)g,
                                   (__attribute__((address_space(3))) void*)l, 16, 0, 0);
}

// bank-aware swizzle for the C-staging tile (stride 128 ushorts = 256B)
static __device__ __forceinline__ int cswz(int row) {
  return (((row & 7) ^ ((row >> 3) & 7)) << 3);
}

// XCD-bijective blockIdx swizzle (requires nwg % 8 == 0)
static __device__ __forceinline__ int2 xcd_remap(int nx) {
  int bid = blockIdx.y * nx + blockIdx.x;
  int nwg = nx * gridDim.y;
  int cpx = nwg >> 3;
  int id = (bid & 7) * cpx + (bid >> 3);
  return make_int2(id % nx, id / nx);
}

// ---------------- fused LayerNorm + x->bf16 ----------------
__global__ __launch_bounds__(256) void lncvt_k(const float* __restrict__ x,
                                               const float* __restrict__ g,
                                               const float* __restrict__ b,
                                               ushort* __restrict__ x_b,
                                               ushort* __restrict__ xn_b) {
  __shared__ float red[8];
  int row = blockIdx.x;
  const float4* xr = (const float4*)(x + (size_t)row * DM);
  float4 v = xr[threadIdx.x];
  ushort4 xb4;
  xb4.x = f2bf(v.x); xb4.y = f2bf(v.y); xb4.z = f2bf(v.z); xb4.w = f2bf(v.w);
  ((ushort4*)(x_b + (size_t)row * DM))[threadIdx.x] = xb4;
  float s = v.x + v.y + v.z + v.w;
#pragma unroll
  for (int o = 32; o > 0; o >>= 1) s += __shfl_down(s, o, 64);
  int lane = threadIdx.x & 63, w = threadIdx.x >> 6;
  if (lane == 0) red[w] = s;
  __syncthreads();
  float mu = (red[0] + red[1] + red[2] + red[3]) * (1.0f / DM);
  float dx = v.x - mu, dy = v.y - mu, dz = v.z - mu, dw = v.w - mu;
  float ss = dx * dx + dy * dy + dz * dz + dw * dw;
#pragma unroll
  for (int o = 32; o > 0; o >>= 1) ss += __shfl_down(ss, o, 64);
  if (lane == 0) red[4 + w] = ss;
  __syncthreads();
  float var = (red[4] + red[5] + red[6] + red[7]) * (1.0f / DM);
  float rstd = rsqrtf(var + EPSF);
  float4 gg = ((const float4*)g)[threadIdx.x];
  float4 bb = ((const float4*)b)[threadIdx.x];
  ushort4 o4;
  o4.x = f2bf(dx * rstd * gg.x + bb.x);
  o4.y = f2bf(dy * rstd * gg.y + bb.y);
  o4.z = f2bf(dz * rstd * gg.z + bb.z);
  o4.w = f2bf(dw * rstd * gg.w + bb.w);
  ((ushort4*)(xn_b + (size_t)row * DM))[threadIdx.x] = o4;
}

// ---------------- W [K][N] fp32 -> Wt [N][K] bf16 ----------------
__global__ __launch_bounds__(256) void tconv_k(const float* __restrict__ W,
                                               ushort* __restrict__ Wt, int K, int N) {
  __shared__ ushort tile[32][33];
  int k0 = blockIdx.y * 32, n0 = blockIdx.x * 32;
  int tx = threadIdx.x & 31, ty = threadIdx.x >> 5;
#pragma unroll
  for (int i = 0; i < 4; i++) {
    int k = ty + i * 8;
    tile[k][tx] = f2bf(W[(size_t)(k0 + k) * N + n0 + tx]);
  }
  __syncthreads();
#pragma unroll
  for (int i = 0; i < 4; i++) {
    int n = ty + i * 8;
    Wt[(size_t)(n0 + n) * K + k0 + tx] = tile[tx][n];
  }
}

// ---------------- per-row gate inv-mean: ginv = 1/(mean(gate)+eps) -------
__global__ __launch_bounds__(256) void rowinv_k(const ushort* __restrict__ gate_b,
                                                float* __restrict__ ginv) {
  int row = blockIdx.x * 4 + (threadIdx.x >> 6);
  int l = threadIdx.x & 63;
  const short8* gr = (const short8*)(gate_b + (size_t)row * DM);
  short8 g0 = gr[l * 2], g1 = gr[l * 2 + 1];
  float s = 0.f;
#pragma unroll
  for (int j = 0; j < 8; j++) s += bf2f((ushort)g0[j]) + bf2f((ushort)g1[j]);
#pragma unroll
  for (int o = 1; o < 64; o <<= 1) s += __shfl_xor(s, o, 64);
  if (l == 0) ginv[row] = 1.0f / (s * (1.0f / DM) + EPSF);
}

// ---------------- bf16 MFMA GEMM: C = A @ Wt^T + bias ----------------
// mode 0: fp32 out (Cf). mode 2: sigmoid -> bf16 out (Cb).
#define BM 128
#define BN 128
#define BK 64
__global__ __launch_bounds__(256) void gemm_bf16_k(
    const ushort* __restrict__ A, const ushort* __restrict__ Bt,
    const float* __restrict__ bias, float* __restrict__ Cf,
    ushort* __restrict__ Cb, int ldc, int K, int mode) {
  __shared__ __align__(16) ushort As[BM * BK];
  __shared__ __align__(16) ushort Bs[BN * BK];
  int tid = threadIdx.x, lane = tid & 63, w = tid >> 6;
  int2 bxy = xcd_remap(gridDim.x);
  int m0 = bxy.y * BM, n0 = bxy.x * BN;
  int wr = w >> 1, wc = w & 1;
  f32x4 acc[4][4] = {};
  for (int k0 = 0; k0 < K; k0 += BK) {
#pragma unroll
    for (int j = 0; j < 4; j++) {
      int lu = (w * 4 + j) * 64 + lane;
      int r = lu >> 3;
      int kb = (lu & 7) ^ (r & 7);
      gload_lds16(A + (size_t)(m0 + r) * K + k0 + kb * 8, &As[(w * 4 + j) * 512]);
      gload_lds16(Bt + (size_t)(n0 + r) * K + k0 + kb * 8, &Bs[(w * 4 + j) * 512]);
    }
    __syncthreads();
#pragma unroll
    for (int ks = 0; ks < 2; ks++) {
      short8 af[4], bfr[4];
      int kq = ks * 4 + (lane >> 4);
#pragma unroll
      for (int f = 0; f < 4; f++) {
        int ra = wr * 64 + f * 16 + (lane & 15);
        af[f] = *(const short8*)&As[(ra * 8 + (kq ^ (ra & 7))) * 8];
        int rb = wc * 64 + f * 16 + (lane & 15);
        bfr[f] = *(const short8*)&Bs[(rb * 8 + (kq ^ (rb & 7))) * 8];
      }
#pragma unroll
      for (int i = 0; i < 4; i++)
#pragma unroll
        for (int j2 = 0; j2 < 4; j2++)
          acc[i][j2] = __builtin_amdgcn_mfma_f32_16x16x32_bf16(af[i], bfr[j2], acc[i][j2], 0, 0, 0);
    }
    __syncthreads();
  }
#pragma unroll
  for (int i = 0; i < 4; i++) {
#pragma unroll
    for (int j2 = 0; j2 < 4; j2++) {
      int col = n0 + wc * 64 + j2 * 16 + (lane & 15);
      float bv = bias[col];
#pragma unroll
      for (int r = 0; r < 4; r++) {
        int row = m0 + wr * 64 + i * 16 + (lane >> 4) * 4 + r;
        float v = acc[i][j2][r] + bv;
        if (mode == 2) {
          v = 1.0f / (1.0f + expf(-v));
          Cb[(size_t)row * ldc + col] = f2bf(v);
        } else {
          Cf[(size_t)row * ldc + col] = v;
        }
      }
    }
  }
}

// ---------------- qkv GEMM with LDS-staged coalesced epilogue ------------
// q,k: *gate(bf16)*ginv[row], relu^2 + eps. v: plain.
__global__ __launch_bounds__(256) void gemm_qkv_k(
    const ushort* __restrict__ A, const ushort* __restrict__ Bt,
    const float* __restrict__ bias, const ushort* __restrict__ gate_b,
    const float* __restrict__ ginv,
    ushort* __restrict__ qb, ushort* __restrict__ kb,
    ushort* __restrict__ kt, ushort* __restrict__ vt, int K) {
  __shared__ __align__(16) ushort sh[16896];  // As|Bs during K-loop; gate/C tile after
  __shared__ float ginvs[128];
  ushort* As = sh;
  ushort* Bs = sh + BM * BK;
  int tid = threadIdx.x, lane = tid & 63, w = tid >> 6;
  int2 bxy = xcd_remap(gridDim.x);
  int m0 = bxy.y * BM, n0 = bxy.x * BN;
  int wr = w >> 1, wc = w & 1;
  f32x4 acc[4][4] = {};
  for (int k0 = 0; k0 < K; k0 += BK) {
#pragma unroll
    for (int j = 0; j < 4; j++) {
      int lu = (w * 4 + j) * 64 + lane;
      int r = lu >> 3;
      int kb2 = (lu & 7) ^ (r & 7);
      gload_lds16(A + (size_t)(m0 + r) * K + k0 + kb2 * 8, &As[(w * 4 + j) * 512]);
      gload_lds16(Bt + (size_t)(n0 + r) * K + k0 + kb2 * 8, &Bs[(w * 4 + j) * 512]);
    }
    __syncthreads();
#pragma unroll
    for (int ks = 0; ks < 2; ks++) {
      short8 af[4], bfr[4];
      int kq = ks * 4 + (lane >> 4);
#pragma unroll
      for (int f = 0; f < 4; f++) {
        int ra = wr * 64 + f * 16 + (lane & 15);
        af[f] = *(const short8*)&As[(ra * 8 + (kq ^ (ra & 7))) * 8];
        int rb = wc * 64 + f * 16 + (lane & 15);
        bfr[f] = *(const short8*)&Bs[(rb * 8 + (kq ^ (rb & 7))) * 8];
      }
#pragma unroll
      for (int i = 0; i < 4; i++)
#pragma unroll
        for (int j2 = 0; j2 < 4; j2++)
          acc[i][j2] = __builtin_amdgcn_mfma_f32_16x16x32_bf16(af[i], bfr[j2], acc[i][j2], 0, 0, 0);
    }
    __syncthreads();
  }
  // ---- epilogue ----
  int region = n0 >> 10;     // 0=q, 1=k, 2=v
  int n0b = n0 & 1023;
  int h0 = n0b >> 6;
  if (region < 2) {
    if (tid < 128) ginvs[tid] = ginv[m0 + tid];
#pragma unroll
    for (int it = 0; it < 8; it++) {
      int e = it * 256 + tid;
      int row = e >> 4, ch = e & 15;
      *(short8*)&sh[row * 132 + ch * 8] =
          *(const short8*)&gate_b[(size_t)(m0 + row) * DM + n0b + ch * 8];
    }
    __syncthreads();
#pragma unroll
    for (int i = 0; i < 4; i++) {
#pragma unroll
      for (int j2 = 0; j2 < 4; j2++) {
        int cl = wc * 64 + j2 * 16 + (lane & 15);
        float bv = bias[n0 + cl];
        int rl0 = wr * 64 + i * 16 + (lane >> 4) * 4;
#pragma unroll
        for (int r = 0; r < 4; r++) {
          float gv = bf2f(sh[(rl0 + r) * 132 + cl]) * ginvs[rl0 + r];
          float v = (acc[i][j2][r] + bv) * gv;
          v = fmaxf(v, 0.0f);
          acc[i][j2][r] = v * v + EPSF;
        }
      }
    }
    __syncthreads();
  } else {
#pragma unroll
    for (int i = 0; i < 4; i++)
#pragma unroll
      for (int j2 = 0; j2 < 4; j2++) {
        int cl = wc * 64 + j2 * 16 + (lane & 15);
        float bv = bias[n0 + cl];
#pragma unroll
        for (int r = 0; r < 4; r++) acc[i][j2][r] += bv;
      }
  }
  // pack C tile into LDS, swizzled
#pragma unroll
  for (int i = 0; i < 4; i++) {
#pragma unroll
    for (int j2 = 0; j2 < 4; j2++) {
      int cl = wc * 64 + j2 * 16 + (lane & 15);
      int rl0 = wr * 64 + i * 16 + (lane >> 4) * 4;
#pragma unroll
      for (int r = 0; r < 4; r++) {
        int row = rl0 + r;
        sh[row * 128 + (cl ^ cswz(row))] = f2bf(acc[i][j2][r]);
      }
    }
  }
  __syncthreads();
  // coalesced stores
  if (region < 2) {
    ushort* dstRM = (region == 0) ? qb : kb;
#pragma unroll
    for (int it = 0; it < 8; it++) {
      int e = it * 256 + tid;
      int row = e >> 4, ch = e & 15;
      short8 val = *(const short8*)&sh[row * 128 + ((ch * 8) ^ cswz(row))];
      int tglob = m0 + row;
      size_t bh2 = (size_t)(tglob >> 11) * 16 + h0 + (ch >> 3);
      *(short8*)&dstRM[(bh2 * 2048 + (tglob & 2047)) * 64 + (ch & 7) * 8] = val;
    }
  }
  if (region >= 1) {
    ushort* dstT = (region == 1) ? kt : vt;
#pragma unroll
    for (int it = 0; it < 8; it++) {
      int e = it * 256 + tid;
      int tch = e & 15, dkrow = e >> 4;
      short8 val;
#pragma unroll
      for (int j = 0; j < 8; j++) {
        int row = tch * 8 + j;
        val[j] = (short)sh[row * 128 + (dkrow ^ cswz(row))];
      }
      int tglob0 = m0 + tch * 8;
      size_t bh2 = (size_t)(tglob0 >> 11) * 16 + h0 + (dkrow >> 6);
      *(short8*)&dstT[(bh2 * 64 + (dkrow & 63)) * 2048 + (tglob0 & 2047)] = val;
    }
  }
}

// ---- fused chunk-KV + exclusive prefix (running prefix = MFMA C-operand) --
// grid (4 dv-slices, 64 bh), 256 thr. Writes bf16 exclusive-prefix KVb and
// fp32 exclusive-prefix ksum (dv-slice 0 only). No fp32 KVt round-trip.
__global__ __launch_bounds__(256) void chunkpfx_k(const ushort* __restrict__ kt,
                                                  const ushort* __restrict__ vt,
                                                  ushort* __restrict__ KVb,
                                                  float* __restrict__ ksum) {
  int dvs = blockIdx.x, bh = blockIdx.y;
  int tid = threadIdx.x, l = tid & 63, w = tid >> 6;
  int lr = l & 15, lg = l >> 4;
  const ushort* vT = vt + ((size_t)bh * 64 + dvs * 16 + lr) * 2048;  // A rows: dv
  const ushort* kT = kt + ((size_t)bh * 64 + w * 16 + lr) * 2048;    // B rows: dk
  f32x4 run = {0.f, 0.f, 0.f, 0.f};
  float runks = 0.0f;
  short8 a0 = *(const short8*)&vT[lg * 8];
  short8 a1 = *(const short8*)&vT[32 + lg * 8];
  short8 b0 = *(const short8*)&kT[lg * 8];
  short8 b1 = *(const short8*)&kT[32 + lg * 8];
  for (int c = 0; c < 32; c++) {
    // exclusive-prefix store (before accumulating chunk c)
    ushort* dst = KVb + ((size_t)bh * 32 + c) * 4096 +
                  (size_t)(dvs * 16 + lg * 4) * 64 + w * 16 + lr;
    dst[0] = f2bf(run[0]); dst[64] = f2bf(run[1]);
    dst[128] = f2bf(run[2]); dst[192] = f2bf(run[3]);
    if (dvs == 0) {
      // chunk colsum of K for dk = w*16+lr, from the already-loaded B frags
      float s = 0.f;
#pragma unroll
      for (int j = 0; j < 8; j++) s += bf2f((ushort)b0[j]) + bf2f((ushort)b1[j]);
      s += __shfl_xor(s, 16, 64);
      s += __shfl_xor(s, 32, 64);
      if (l < 16) ksum[((size_t)bh * 32 + c) * 64 + w * 16 + l] = runks;
      runks += s;
    }
    int cn = (c + 1) & 31;  // clamped prefetch (last iter re-reads chunk 0, unused)
    short8 na0 = *(const short8*)&vT[cn * 64 + lg * 8];
    short8 na1 = *(const short8*)&vT[cn * 64 + 32 + lg * 8];
    short8 nb0 = *(const short8*)&kT[cn * 64 + lg * 8];
    short8 nb1 = *(const short8*)&kT[cn * 64 + 32 + lg * 8];
    run = __builtin_amdgcn_mfma_f32_16x16x32_bf16(a0, b0, run, 0, 0, 0);
    run = __builtin_amdgcn_mfma_f32_16x16x32_bf16(a1, b1, run, 0, 0, 0);
    a0 = na0; a1 = na1; b0 = nb0; b1 = nb1;
  }
}

// ---------------- pass 3: O^T[dv][t] = KVb·Q + vt·S, S^T = mfma(K,Q) ------
__global__ __launch_bounds__(256) void attn_k(
    const ushort* __restrict__ qb, const ushort* __restrict__ kb,
    const ushort* __restrict__ vt, const ushort* __restrict__ KVb,
    const float* __restrict__ ks, ushort* __restrict__ attnout) {
  int c = blockIdx.x, bh = blockIdx.y;
  int b = bh >> 4, h = bh & 15;
  const ushort* qB = qb + ((size_t)bh * 2048 + (size_t)c * 64) * 64;
  const ushort* kB = kb + ((size_t)bh * 2048 + (size_t)c * 64) * 64;
  const ushort* vT = vt + (size_t)bh * 64 * 2048 + (size_t)c * 64;
  const ushort* kvB = KVb + ((size_t)bh * 32 + c) * 4096;
  const float* ksP = ks + ((size_t)bh * 32 + c) * 64;
  __shared__ __align__(16) char SL[64 * 128];
  __shared__ float denp[4][64];
  __shared__ float den2p[4][64];
  __shared__ float invden[64];
  int tid = threadIdx.x, l = tid & 63, w = tid >> 6;
  int lr = l & 15, lg = l >> 4;
  {
    short8 q0 = *(const short8*)&qB[(size_t)l * 64 + w * 16];
    short8 q1 = *(const short8*)&qB[(size_t)l * 64 + w * 16 + 8];
    float d2 = 0.0f;
#pragma unroll
    for (int j = 0; j < 8; j++) {
      d2 += bf2f((ushort)q0[j]) * ksP[w * 16 + j];
      d2 += bf2f((ushort)q1[j]) * ksP[w * 16 + 8 + j];
    }
    den2p[w][l] = d2;
  }
#pragma unroll
  for (int n = 0; n < 4; n++) {
    f32x4 sa = {0.f, 0.f, 0.f, 0.f};
#pragma unroll
    for (int g = 0; g < 2; g++) {
      short8 a = *(const short8*)&kB[(size_t)(w * 16 + lr) * 64 + g * 32 + lg * 8];
      short8 bq = *(const short8*)&qB[(size_t)(n * 16 + lr) * 64 + g * 32 + lg * 8];
      sa = __builtin_amdgcn_mfma_f32_16x16x32_bf16(a, bq, sa, 0, 0, 0);
    }
    int t = n * 16 + lr;
    int s0 = w * 16 + lg * 4;
    float dsum = 0.0f;
    ushort sb[4];
#pragma unroll
    for (int r = 0; r < 4; r++) {
      float v = (s0 + r <= t) ? sa[r] : 0.0f;
      dsum += v;
      sb[r] = f2bf(v);
    }
    dsum += __shfl_xor(dsum, 16, 64);
    dsum += __shfl_xor(dsum, 32, 64);
    if (l < 16) denp[w][n * 16 + l] = dsum;
    int u = (s0 >> 3) ^ (t & 7);
    uint2 p;
    p.x = sb[0] | ((unsigned)sb[1] << 16);
    p.y = sb[2] | ((unsigned)sb[3] << 16);
    *(uint2*)&SL[t * 128 + u * 16 + (s0 & 7) * 2] = p;
  }
  __syncthreads();
  if (tid < 64) {
    float den = denp[0][tid] + denp[1][tid] + denp[2][tid] + denp[3][tid] +
                den2p[0][tid] + den2p[1][tid] + den2p[2][tid] + den2p[3][tid] + EPSF;
    invden[tid] = 1.0f / den;
  }
  __syncthreads();
#pragma unroll
  for (int n = 0; n < 4; n++) {
    f32x4 oa = {0.f, 0.f, 0.f, 0.f};
#pragma unroll
    for (int g = 0; g < 2; g++) {
      short8 a = *(const short8*)&kvB[(size_t)(w * 16 + lr) * 64 + g * 32 + lg * 8];
      short8 bq = *(const short8*)&qB[(size_t)(n * 16 + lr) * 64 + g * 32 + lg * 8];
      oa = __builtin_amdgcn_mfma_f32_16x16x32_bf16(a, bq, oa, 0, 0, 0);
    }
    int t = n * 16 + lr;
#pragma unroll
    for (int g = 0; g < 2; g++) {
      short8 a = *(const short8*)&vT[(size_t)(w * 16 + lr) * 2048 + g * 32 + lg * 8];
      int u = (g * 4 + lg) ^ (t & 7);
      short8 bs = *(const short8*)&SL[t * 128 + u * 16];
      oa = __builtin_amdgcn_mfma_f32_16x16x32_bf16(a, bs, oa, 0, 0, 0);
    }
    float iv = invden[t];
    ushort ob[4];
#pragma unroll
    for (int r = 0; r < 4; r++) ob[r] = f2bf(oa[r] * iv);
    size_t tok = (size_t)b * 2048 + (size_t)c * 64 + t;
    uint2 p;
    p.x = ob[0] | ((unsigned)ob[1] << 16);
    p.y = ob[2] | ((unsigned)ob[3] << 16);
    *(uint2*)&attnout[tok * 1024 + h * 64 + w * 16 + lg * 4] = p;
  }
}

extern "C" void kernel_launch(void* const* d_in, const int* in_sizes, int n_in,
                              void* d_out, int out_size, void* d_ws, size_t ws_size,
                              hipStream_t stream) {
  const float* x      = (const float*)d_in[0];
  const float* ln_g   = (const float*)d_in[1];
  const float* ln_b   = (const float*)d_in[2];
  const float* W_qkv  = (const float*)d_in[3];
  const float* b_qkv  = (const float*)d_in[4];
  const float* W_gate = (const float*)d_in[5];
  const float* b_gate = (const float*)d_in[6];
  const float* W_proj = (const float*)d_in[7];
  const float* b_proj = (const float*)d_in[8];
  float* out = (float*)d_out;

  char* wsb = (char*)d_ws;
  const size_t TD = (size_t)TOK * DM;
  const size_t SLOT = TD * 2;
  ushort* x_b     = (ushort*)(wsb + 0 * SLOT);  // dead after gate GEMM
  ushort* attnout = (ushort*)(wsb + 0 * SLOT);
  ushort* xn_b    = (ushort*)(wsb + 1 * SLOT);
  ushort* qb      = (ushort*)(wsb + 2 * SLOT);
  ushort* kb      = (ushort*)(wsb + 3 * SLOT);
  ushort* kt      = (ushort*)(wsb + 4 * SLOT);
  ushort* vt      = (ushort*)(wsb + 5 * SLOT);
  ushort* gate_b  = (ushort*)(wsb + 6 * SLOT);  // dead after qkv GEMM
  ushort* Wt_gate = (ushort*)(wsb + 8 * SLOT);  // dead after gate GEMM
  ushort* Wt_qkv  = (ushort*)(wsb + 8 * SLOT);  // dead after qkv GEMM
  ushort* KVb     = (ushort*)(wsb + 8 * SLOT);
  ushort* Wt_proj = (ushort*)(wsb + 9 * SLOT);
  float*  ksum    = (float*)(wsb + 9 * SLOT + 8 * 1024 * 1024);   // 512 KB
  float*  ginv    = (float*)(wsb + 9 * SLOT + 12 * 1024 * 1024);  // 32 KB

  // 1) x -> x_b (bf16) and LayerNorm -> xn_b (bf16), one x read
  lncvt_k<<<TOK, 256, 0, stream>>>(x, ln_g, ln_b, x_b, xn_b);
  // 2) W_gate -> transposed bf16
  tconv_k<<<dim3(DM / 32, DM / 32), 256, 0, stream>>>(W_gate, Wt_gate, DM, DM);
  // 3) gate = sigmoid(x @ W_gate + b_gate) -> bf16 (raw, un-normalized)
  gemm_bf16_k<<<dim3(DM / BN, TOK / BM), 256, 0, stream>>>(x_b, Wt_gate, b_gate, nullptr,
                                                           gate_b, DM, DM, 2);
  // 4) ginv[row] = 1/(row-mean(gate)+eps)
  rowinv_k<<<TOK / 4, 256, 0, stream>>>(gate_b, ginv);
  // 5) W_qkv -> transposed bf16
  tconv_k<<<dim3(3 * DM / 32, DM / 32), 256, 0, stream>>>(W_qkv, Wt_qkv, DM, 3 * DM);
  // 6) qkv GEMM -> qb/kb + kt/vt (bf16), fused gate*ginv+relu^2
  gemm_qkv_k<<<dim3(3 * DM / BN, TOK / BM), 256, 0, stream>>>(xn_b, Wt_qkv, b_qkv, gate_b,
                                                              ginv, qb, kb, kt, vt, DM);
  // 7) fused chunk-KV + exclusive prefix -> KVb (bf16) + ksum (fp32)
  chunkpfx_k<<<dim3(4, 64), 256, 0, stream>>>(kt, vt, KVb, ksum);
  // 8) W_proj -> transposed bf16
  tconv_k<<<dim3(DM / 32, DM / 32), 256, 0, stream>>>(W_proj, Wt_proj, DM, DM);
  // 9) chunk outputs -> attnout bf16 row-major
  attn_k<<<dim3(32, 64), 256, 0, stream>>>(qb, kb, vt, KVb, ksum, attnout);
  // 10) out = attn @ W_proj + b_proj (fp32 out)
  gemm_bf16_k<<<dim3(DM / BN, TOK / BM), 256, 0, stream>>>(attnout, Wt_proj, b_proj, out,
                                                           nullptr, DM, DM, 0);
}